// Round 1
// baseline (2736.329 us; speedup 1.0000x reference)
//
#include <hip/hip_runtime.h>

// ---------------- constants ----------------
#define Bq 8
#define Tq 129
#define Sq 128
#define Hq 512
#define Nq 64
#define NLq 4
#define NEq 128
#define Vq 18

__device__ __forceinline__ float gelu_f(float x) {
  return 0.5f * x * (1.0f + erff(x * 0.70710678118654752f));
}

// ---------------- conv1: [1024,4,84,84] -> [1024,32,20,20], k8 s4, ReLU ----------------
__global__ __launch_bounds__(256) void conv1_k(const float* __restrict__ states,
    const float* __restrict__ w, const float* __restrict__ bias, float* __restrict__ out) {
  int fr = blockIdx.y;
  int b = fr >> 7, s = fr & 127;
  const float* in = states + (size_t)(b * Tq + s + 1) * (4 * 84 * 84);
  int i = blockIdx.x * 256 + threadIdx.x;   // < 12800
  int oc = i / 400, p = i - oc * 400, oy = p / 20, ox = p - oy * 20;
  float acc = bias[oc];
  const float* wp = w + oc * 256;
  for (int ic = 0; ic < 4; ic++) {
    const float* inc = in + ic * 84 * 84;
    const float* wic = wp + ic * 64;
    #pragma unroll
    for (int ky = 0; ky < 8; ky++) {
      const float* ip = inc + (oy * 4 + ky) * 84 + ox * 4;
      const float* wr = wic + ky * 8;
      #pragma unroll
      for (int kx = 0; kx < 8; kx++) acc = fmaf(ip[kx], wr[kx], acc);
    }
  }
  out[(size_t)fr * 12800 + i] = fmaxf(acc, 0.f);
}

// ---------------- conv2: [1024,32,20,20] -> [1024,64,9,9], k4 s2, ReLU ----------------
__global__ __launch_bounds__(256) void conv2_k(const float* __restrict__ in_,
    const float* __restrict__ w, const float* __restrict__ bias, float* __restrict__ out) {
  int fr = blockIdx.y;
  const float* in = in_ + (size_t)fr * 12800;
  int i = blockIdx.x * 256 + threadIdx.x;
  if (i >= 5184) return;
  int oc = i / 81, p = i - oc * 81, oy = p / 9, ox = p - oy * 9;
  float acc = bias[oc];
  const float* wp = w + oc * 512;
  for (int ic = 0; ic < 32; ic++) {
    const float* inc = in + (ic * 20 + oy * 2) * 20 + ox * 2;
    const float* wic = wp + ic * 16;
    #pragma unroll
    for (int ky = 0; ky < 4; ky++) {
      #pragma unroll
      for (int kx = 0; kx < 4; kx++)
        acc = fmaf(inc[ky * 20 + kx], wic[ky * 4 + kx], acc);
    }
  }
  out[(size_t)fr * 5184 + i] = fmaxf(acc, 0.f);
}

// ---------------- conv3: [1024,64,9,9] -> [1024,64,7,7], k3 s1, ReLU ----------------
__global__ __launch_bounds__(256) void conv3_k(const float* __restrict__ in_,
    const float* __restrict__ w, const float* __restrict__ bias, float* __restrict__ out) {
  int fr = blockIdx.y;
  const float* in = in_ + (size_t)fr * 5184;
  int i = blockIdx.x * 256 + threadIdx.x;
  if (i >= 3136) return;
  int oc = i / 49, p = i - oc * 49, oy = p / 7, ox = p - oy * 7;
  float acc = bias[oc];
  const float* wp = w + oc * 576;
  for (int ic = 0; ic < 64; ic++) {
    const float* inc = in + (ic * 9 + oy) * 9 + ox;
    const float* wic = wp + ic * 9;
    #pragma unroll
    for (int ky = 0; ky < 3; ky++) {
      #pragma unroll
      for (int kx = 0; kx < 3; kx++)
        acc = fmaf(inc[ky * 9 + kx], wic[ky * 3 + kx], acc);
    }
  }
  out[(size_t)fr * 3136 + i] = fmaxf(acc, 0.f);
}

// ---------------- generic tiled f32 GEMM: C[m,n] = post(preA @ W + bias) ----------------
// PRE: 0 none, 1 gelu on A.  POST: 0 none, 1 tanh, 2 gelu then + res (residual)
template<int PRE, int POST>
__global__ __launch_bounds__(256) void gemm_k(const float* __restrict__ A,
    const float* __restrict__ W, const float* __restrict__ bias,
    const float* __restrict__ res, float* __restrict__ C,
    int M, int K, int N, int ldc) {
  __shared__ float As[16][68];   // [k][m], padded: 2-way write conflict only, 16B-aligned rows
  __shared__ float Ws[16][64];   // [k][n]
  int tid = threadIdx.x;
  int bm = blockIdx.y * 64, bn = blockIdx.x * 64;
  int tx = tid & 15, ty = tid >> 4;
  float acc[4][4] = {};
  for (int k0 = 0; k0 < K; k0 += 16) {
    #pragma unroll
    for (int i = 0; i < 4; i++) {
      int idx = tid + i * 256;           // 0..1023
      int m = idx >> 4, kk = idx & 15;
      float a = A[(size_t)(bm + m) * K + k0 + kk];
      if (PRE == 1) a = gelu_f(a);
      As[kk][m] = a;
    }
    #pragma unroll
    for (int i = 0; i < 4; i++) {
      int idx = tid + i * 256;
      int kk = idx >> 6, n = idx & 63;
      Ws[kk][n] = (bn + n < N) ? W[(size_t)(k0 + kk) * N + bn + n] : 0.f;
    }
    __syncthreads();
    #pragma unroll
    for (int kk = 0; kk < 16; kk++) {
      float a0 = As[kk][ty * 4 + 0], a1 = As[kk][ty * 4 + 1];
      float a2 = As[kk][ty * 4 + 2], a3 = As[kk][ty * 4 + 3];
      float b0 = Ws[kk][tx * 4 + 0], b1 = Ws[kk][tx * 4 + 1];
      float b2 = Ws[kk][tx * 4 + 2], b3 = Ws[kk][tx * 4 + 3];
      acc[0][0] = fmaf(a0, b0, acc[0][0]); acc[0][1] = fmaf(a0, b1, acc[0][1]);
      acc[0][2] = fmaf(a0, b2, acc[0][2]); acc[0][3] = fmaf(a0, b3, acc[0][3]);
      acc[1][0] = fmaf(a1, b0, acc[1][0]); acc[1][1] = fmaf(a1, b1, acc[1][1]);
      acc[1][2] = fmaf(a1, b2, acc[1][2]); acc[1][3] = fmaf(a1, b3, acc[1][3]);
      acc[2][0] = fmaf(a2, b0, acc[2][0]); acc[2][1] = fmaf(a2, b1, acc[2][1]);
      acc[2][2] = fmaf(a2, b2, acc[2][2]); acc[2][3] = fmaf(a2, b3, acc[2][3]);
      acc[3][0] = fmaf(a3, b0, acc[3][0]); acc[3][1] = fmaf(a3, b1, acc[3][1]);
      acc[3][2] = fmaf(a3, b2, acc[3][2]); acc[3][3] = fmaf(a3, b3, acc[3][3]);
    }
    __syncthreads();
  }
  #pragma unroll
  for (int i = 0; i < 4; i++) {
    #pragma unroll
    for (int j = 0; j < 4; j++) {
      int m = bm + ty * 4 + i, n = bn + tx * 4 + j;
      if (n < N) {
        float v = acc[i][j] + (bias ? bias[n] : 0.f);
        if (POST == 1) v = tanhf(v);
        if (POST == 2) v = gelu_f(v) + res[(size_t)m * ldc + n];
        C[(size_t)m * ldc + n] = v;
      }
    }
  }
}

// ---------------- action + rtg embeddings into uin[:,128:384] ----------------
__global__ __launch_bounds__(256) void embed_k(const int* __restrict__ actions,
    const float* __restrict__ rtgs, const float* __restrict__ act_emb,
    const float* __restrict__ ret_w, const float* __restrict__ ret_b,
    float* __restrict__ uin) {
  int f = blockIdx.x;
  int b = f >> 7, s = f & 127;
  int e = threadIdx.x;
  if (e < 128) {
    int a = actions[b * Tq + s];
    uin[(size_t)f * 384 + 128 + e] = tanhf(act_emb[a * NEq + e]);
  } else {
    int ee = e - 128;
    uin[(size_t)f * 384 + 256 + ee] =
        tanhf(fmaf(rtgs[b * Tq + s], ret_w[ee], ret_b[ee]));
  }
}

// ---------------- S4 kernel generation: Kt[layer][l][h] ----------------
__global__ __launch_bounds__(128) void s4k_gen(const float* __restrict__ log_dt,
    const float* __restrict__ A_re, const float* __restrict__ A_im,
    const float* __restrict__ C_re, const float* __restrict__ C_im,
    float* __restrict__ Kt) {
  int lh = blockIdx.x;            // layer*512 + h
  int l = threadIdx.x;            // 0..127
  float fl = (float)l;
  float dt = expf(log_dt[lh]);
  const float* Ar = A_re + (size_t)lh * Nq;
  const float* Ai = A_im + (size_t)lh * Nq;
  const float* Cr = C_re + (size_t)lh * Nq;
  const float* Ci = C_im + (size_t)lh * Nq;
  float acc = 0.f;
  for (int n = 0; n < Nq; n++) {
    float ar = Ar[n], ai = Ai[n];
    float al = dt * ar, be = dt * ai;
    float er = expf(al);
    float zr = er * cosf(be) - 1.0f;        // exp(dtA) - 1
    float zi = er * sinf(be);
    float den = 1.0f / (ar * ar + ai * ai); // / A
    float wr = (zr * ar + zi * ai) * den;
    float wi = (zi * ar - zr * ai) * den;
    float cr = Cr[n] * wr - Ci[n] * wi;     // Ceff
    float ci = Cr[n] * wi + Ci[n] * wr;
    float e2 = expf(al * fl);               // exp(dtA)^l
    float vr = e2 * cosf(be * fl);
    float vi = e2 * sinf(be * fl);
    acc += cr * vr - ci * vi;
  }
  int layer = lh >> 9, h = lh & 511;
  Kt[((size_t)layer * Sq + l) * Hq + h] = 2.0f * acc;
}

// ---------------- layernorm over H=512, one wave per row ----------------
__global__ __launch_bounds__(64) void ln_k(const float* __restrict__ y,
    const float* __restrict__ g, const float* __restrict__ b, float* __restrict__ r) {
  int row = blockIdx.x;
  const float* x = y + (size_t)row * Hq;
  int lane = threadIdx.x;
  float v[8], s = 0.f, s2 = 0.f;
  #pragma unroll
  for (int j = 0; j < 8; j++) {
    v[j] = x[lane + j * 64];
    s += v[j];
    s2 += v[j] * v[j];
  }
  #pragma unroll
  for (int o = 32; o >= 1; o >>= 1) {
    s += __shfl_xor(s, o);
    s2 += __shfl_xor(s2, o);
  }
  float mu = s * (1.f / Hq);
  float var = s2 * (1.f / Hq) - mu * mu;
  float inv = rsqrtf(var + 1e-5f);
  float* out = r + (size_t)row * Hq;
  #pragma unroll
  for (int j = 0; j < 8; j++) {
    int h = lane + j * 64;
    out[h] = (v[j] - mu) * inv * g[h] + b[h];
  }
}

// ---------------- causal conv along sequence: c[b,s,h] = sum_j Kt[j][h]*r[b,s-j,h] + D[h]*r[b,s,h] ----
__global__ __launch_bounds__(512) void sconv_k(const float* __restrict__ r,
    const float* __restrict__ Kt, const float* __restrict__ D, float* __restrict__ c) {
  int s = blockIdx.x, b = blockIdx.y;
  int h = threadIdx.x;
  const float* rb = r + (size_t)b * Sq * Hq + h;
  float acc = D[h] * rb[(size_t)s * Hq];
  for (int j = 0; j <= s; j++)
    acc = fmaf(Kt[(size_t)j * Hq + h], rb[(size_t)(s - j) * Hq], acc);
  c[((size_t)b * Sq + s) * Hq + h] = acc;
}

// ---------------- host ----------------
extern "C" void kernel_launch(void* const* d_in, const int* in_sizes, int n_in,
                              void* d_out, int out_size, void* d_ws, size_t ws_size,
                              hipStream_t stream) {
  const float* states  = (const float*)d_in[0];
  const int*   actions = (const int*)  d_in[1];
  const float* rtgs    = (const float*)d_in[2];
  const float* enc_w1  = (const float*)d_in[3];
  const float* enc_b1  = (const float*)d_in[4];
  const float* enc_w2  = (const float*)d_in[5];
  const float* enc_b2  = (const float*)d_in[6];
  const float* enc_w3  = (const float*)d_in[7];
  const float* enc_b3  = (const float*)d_in[8];
  const float* enc_lw  = (const float*)d_in[9];
  const float* enc_lb  = (const float*)d_in[10];
  const float* ret_w   = (const float*)d_in[11];
  const float* ret_b   = (const float*)d_in[12];
  const float* act_emb = (const float*)d_in[13];
  const float* proj_w  = (const float*)d_in[14];
  const float* proj_b  = (const float*)d_in[15];
  const float* pre_w   = (const float*)d_in[16];
  const float* pre_b   = (const float*)d_in[17];
  const float* ln_g    = (const float*)d_in[18];
  const float* ln_b    = (const float*)d_in[19];
  const float* log_dt  = (const float*)d_in[20];
  const float* A_re    = (const float*)d_in[21];
  const float* A_im    = (const float*)d_in[22];
  const float* C_re    = (const float*)d_in[23];
  const float* C_im    = (const float*)d_in[24];
  const float* Dp      = (const float*)d_in[25];
  const float* aft_w   = (const float*)d_in[26];
  const float* aft_b   = (const float*)d_in[27];
  const float* out_w   = (const float*)d_in[28];

  float* ws = (float*)d_ws;
  // layout (floats); peak = x1+x2 = 18,415,616 floats ≈ 73.7 MB
  float* x1  = ws;                        // 1024*32*20*20 = 13,107,200
  float* x2  = x1 + 13107200;             // 1024*64*9*9   =  5,308,416
  // after conv3, x1 region is dead -> reuse from offset 0
  float* x3  = ws;                        // 1024*64*7*7   =  3,211,264
  float* uin = x3 + 3211264;              // 1024*384      =    393,216
  float* u   = uin + 393216;              // 1024*512      =    524,288
  float* y   = u + 524288;                // 524,288
  float* r   = y + 524288;                // 524,288
  float* c   = r + 524288;                // 524,288
  float* Kt  = c + 524288;                // 4*128*512     =    262,144 (ends < x1 end)

  // encoder
  conv1_k<<<dim3(50, 1024), 256, 0, stream>>>(states, enc_w1, enc_b1, x1);
  conv2_k<<<dim3(21, 1024), 256, 0, stream>>>(x1, enc_w2, enc_b2, x2);
  conv3_k<<<dim3(13, 1024), 256, 0, stream>>>(x2, enc_w3, enc_b3, x3);
  // se = tanh(x3 @ enc_lw + enc_lb) -> uin[:, 0:128]
  gemm_k<0, 1><<<dim3(2, 16), 256, 0, stream>>>(x3, enc_lw, enc_lb, nullptr, uin,
                                                1024, 3136, 128, 384);
  embed_k<<<1024, 256, 0, stream>>>(actions, rtgs, act_emb, ret_w, ret_b, uin);
  // u = uin @ proj_w + proj_b
  gemm_k<0, 0><<<dim3(8, 16), 256, 0, stream>>>(uin, proj_w, proj_b, nullptr, u,
                                                1024, 384, 512, 512);
  // y = gelu(u) @ pre_w + pre_b
  gemm_k<1, 0><<<dim3(8, 16), 256, 0, stream>>>(u, pre_w, pre_b, nullptr, y,
                                                1024, 512, 512, 512);
  // S4 kernels for all layers
  s4k_gen<<<2048, 128, 0, stream>>>(log_dt, A_re, A_im, C_re, C_im, Kt);

  for (int i = 0; i < NLq; i++) {
    ln_k<<<1024, 64, 0, stream>>>(y, ln_g + i * Hq, ln_b + i * Hq, r);
    sconv_k<<<dim3(128, 8), 512, 0, stream>>>(r, Kt + (size_t)i * Sq * Hq,
                                              Dp + i * Hq, c);
    // y = gelu(gelu(c) @ aft_w + aft_b) + y
    gemm_k<1, 2><<<dim3(8, 16), 256, 0, stream>>>(c, aft_w + (size_t)i * Hq * Hq,
                                                  aft_b + i * Hq, y, y,
                                                  1024, 512, 512, 512);
  }
  // logits = y @ out_w
  gemm_k<0, 0><<<dim3(1, 16), 256, 0, stream>>>(y, out_w, nullptr, nullptr,
                                                (float*)d_out, 1024, 512, Vq, Vq);
}

// Round 2
// 979.740 us; speedup vs baseline: 2.7929x; 2.7929x over previous
//
#include <hip/hip_runtime.h>

// ---------------- constants ----------------
#define Bq 8
#define Tq 129
#define Sq 128
#define Hq 512
#define Nq 64
#define NLq 4
#define NEq 128
#define Vq 18

typedef unsigned short u16;
typedef __attribute__((ext_vector_type(8))) short short8v;   // 8 bf16 (4 VGPRs), MFMA A/B frag
typedef __attribute__((ext_vector_type(4))) float f32x4;     // MFMA C/D frag

__device__ __forceinline__ float gelu_f(float x) {
  return 0.5f * x * (1.0f + erff(x * 0.70710678118654752f));
}

__device__ __forceinline__ u16 f2b(float x) {   // f32 -> bf16, round-to-nearest-even
  union { float f; unsigned int u; } v; v.f = x;
  unsigned int r = v.u + 0x7FFFu + ((v.u >> 16) & 1u);
  return (u16)(r >> 16);
}

// ---------------- weight prep: permute conv weights to bf16 B[k][n] ----------------
// B1[ic*64+ky*8+kx][oc=32]  B2[(ky*4+kx)*32+ic][oc=64]  B3[(ky*3+kx)*64+ic][oc=64]
__global__ __launch_bounds__(256) void wprep_k(const float* __restrict__ w1,
    const float* __restrict__ w2, const float* __restrict__ w3,
    u16* __restrict__ B1, u16* __restrict__ B2, u16* __restrict__ B3) {
  int i = blockIdx.x * 256 + threadIdx.x;
  if (i < 8192) {                       // conv1: 256 x 32
    int k = i >> 5, n = i & 31;
    int ic = k >> 6, ky = (k >> 3) & 7, kx = k & 7;
    B1[i] = f2b(w1[((n * 4 + ic) * 8 + ky) * 8 + kx]);
  } else if (i < 8192 + 32768) {        // conv2: 512 x 64
    int j = i - 8192;
    int k = j >> 6, n = j & 63;
    int kyx = k >> 5, ic = k & 31, ky = kyx >> 2, kx = kyx & 3;
    B2[j] = f2b(w2[((n * 32 + ic) * 4 + ky) * 4 + kx]);
  } else if (i < 8192 + 32768 + 36864) { // conv3: 576 x 64
    int j = i - 40960;
    int k = j >> 6, n = j & 63;
    int ic = k & 63, kyx = k >> 6, ky = kyx / 3, kx = kyx % 3;
    B3[j] = f2b(w3[((n * 64 + ic) * 3 + ky) * 3 + kx]);
  }
}

// ---------------- conv1 MFMA: [4,84,84]f32 -> [400 pos][32 oc]bf16, k8 s4, ReLU -------
// im2col: M=400 (oy*20+ox), N=32, K=256 (ic*64+ky*8+kx). One frame per block, 4 waves.
__global__ __launch_bounds__(256) void conv1_mfma(const float* __restrict__ states,
    const u16* __restrict__ B1, const float* __restrict__ bias, u16* __restrict__ out) {
  __shared__ u16 lds[28224];            // [ic][84][84] bf16 = 56448 B
  int fr = blockIdx.x;
  int b = fr >> 7, s = fr & 127;
  const float* in = states + (size_t)(b * Tq + s + 1) * 28224;
  int tid = threadIdx.x;
  // stage frame: f32 -> bf16
  #pragma unroll
  for (int it = 0; it < 28; it++) {
    int idx = tid + it * 256;
    if (idx < 7056) {
      float4 v = ((const float4*)in)[idx];
      ushort4 uv;
      uv.x = f2b(v.x); uv.y = f2b(v.y); uv.z = f2b(v.z); uv.w = f2b(v.w);
      *(ushort4*)&lds[idx * 4] = uv;
    }
  }
  int lane = tid & 63, w = tid >> 6;
  int q = lane >> 4, r = lane & 15;
  // B fragments: both n-tiles, 8 k-steps, kept in VGPRs
  short8v bfr[2][8];
  #pragma unroll
  for (int nt = 0; nt < 2; nt++)
    #pragma unroll
    for (int ks = 0; ks < 8; ks++) {
      int k0 = ks * 32 + q * 8;
      #pragma unroll
      for (int j = 0; j < 8; j++)
        bfr[nt][ks][j] = (short)B1[(k0 + j) * 32 + nt * 16 + r];
    }
  __syncthreads();
  for (int mt = w; mt < 25; mt += 4) {
    int m = mt * 16 + r;                // A-row position
    int oy = m / 20, ox = m % 20;
    f32x4 acc0 = {0.f, 0.f, 0.f, 0.f}, acc1 = {0.f, 0.f, 0.f, 0.f};
    #pragma unroll
    for (int ks = 0; ks < 8; ks++) {
      int k0 = ks * 32 + q * 8;
      int ic = k0 >> 6, ky = (k0 >> 3) & 7;
      int ai = ic * 7056 + (oy * 4 + ky) * 84 + ox * 4;  // 8 contiguous bf16, 8B aligned
      ushort4 lo = *(const ushort4*)&lds[ai];
      ushort4 hi = *(const ushort4*)&lds[ai + 4];
      short8v av;
      av[0] = (short)lo.x; av[1] = (short)lo.y; av[2] = (short)lo.z; av[3] = (short)lo.w;
      av[4] = (short)hi.x; av[5] = (short)hi.y; av[6] = (short)hi.z; av[7] = (short)hi.w;
      acc0 = __builtin_amdgcn_mfma_f32_16x16x32_bf16(av, bfr[0][ks], acc0, 0, 0, 0);
      acc1 = __builtin_amdgcn_mfma_f32_16x16x32_bf16(av, bfr[1][ks], acc1, 0, 0, 0);
    }
    #pragma unroll
    for (int reg = 0; reg < 4; reg++) {
      int pos = mt * 16 + q * 4 + reg;
      out[(size_t)fr * 12800 + pos * 32 + r]      = f2b(fmaxf(acc0[reg] + bias[r], 0.f));
      out[(size_t)fr * 12800 + pos * 32 + 16 + r] = f2b(fmaxf(acc1[reg] + bias[16 + r], 0.f));
    }
  }
}

// ---------------- conv2 MFMA: [20,20,32]bf16 -> [81 pos][64 oc]bf16, k4 s2, ReLU ------
// M=81 (oy*9+ox), N=64, K=512 ((ky*4+kx)*32+ic). Wave w owns n-tile w.
__global__ __launch_bounds__(256) void conv2_mfma(const u16* __restrict__ in_,
    const u16* __restrict__ B2, const float* __restrict__ bias, u16* __restrict__ out) {
  __shared__ u16 lds[12800];            // [pos][32] bf16 = 25600 B
  int fr = blockIdx.x;
  int tid = threadIdx.x;
  const short8v* src = (const short8v*)(in_ + (size_t)fr * 12800);
  short8v* dst = (short8v*)lds;
  #pragma unroll
  for (int it = 0; it < 7; it++) {
    int idx = tid + it * 256;
    if (idx < 1600) dst[idx] = src[idx];
  }
  int lane = tid & 63, w = tid >> 6;
  int q = lane >> 4, r = lane & 15;
  int n = w * 16 + r;
  short8v bfr[16];
  #pragma unroll
  for (int ks = 0; ks < 16; ks++) {
    int k0 = ks * 32 + q * 8;
    #pragma unroll
    for (int j = 0; j < 8; j++)
      bfr[ks][j] = (short)B2[(k0 + j) * 64 + n];
  }
  __syncthreads();
  float bn = bias[n];
  #pragma unroll
  for (int mt = 0; mt < 6; mt++) {
    int m = mt * 16 + r; if (m > 80) m = 80;
    int oy = m / 9, ox = m % 9;
    f32x4 acc = {0.f, 0.f, 0.f, 0.f};
    #pragma unroll
    for (int ks = 0; ks < 16; ks++) {
      int ky = ks >> 2, kx = ks & 3;
      int ai = ((oy * 2 + ky) * 20 + ox * 2 + kx) * 32 + q * 8;  // 16B aligned
      short8v av = *(const short8v*)&lds[ai];
      acc = __builtin_amdgcn_mfma_f32_16x16x32_bf16(av, bfr[ks], acc, 0, 0, 0);
    }
    #pragma unroll
    for (int reg = 0; reg < 4; reg++) {
      int pos = mt * 16 + q * 4 + reg;
      if (pos < 81)
        out[(size_t)fr * 5184 + pos * 64 + n] = f2b(fmaxf(acc[reg] + bn, 0.f));
    }
  }
}

// ---------------- conv3 MFMA: [9,9,64]bf16 -> f32 [oc=64][49 pos], k3 s1, ReLU --------
// M=49 (oy*7+ox), N=64, K=576 ((ky*3+kx)*64+ic). Output in reference flatten order.
__global__ __launch_bounds__(256) void conv3_mfma(const u16* __restrict__ in_,
    const u16* __restrict__ B3, const float* __restrict__ bias, float* __restrict__ out) {
  __shared__ u16 lds[5184];             // [pos][64] bf16 = 10368 B
  int fr = blockIdx.x;
  int tid = threadIdx.x;
  const short8v* src = (const short8v*)(in_ + (size_t)fr * 5184);
  short8v* dst = (short8v*)lds;
  #pragma unroll
  for (int it = 0; it < 3; it++) {
    int idx = tid + it * 256;
    if (idx < 648) dst[idx] = src[idx];
  }
  int lane = tid & 63, w = tid >> 6;
  int q = lane >> 4, r = lane & 15;
  int n = w * 16 + r;
  short8v bfr[18];
  #pragma unroll
  for (int ks = 0; ks < 18; ks++) {
    int k0 = ks * 32 + q * 8;
    #pragma unroll
    for (int j = 0; j < 8; j++)
      bfr[ks][j] = (short)B3[(k0 + j) * 64 + n];
  }
  __syncthreads();
  float bn = bias[n];
  #pragma unroll
  for (int mt = 0; mt < 4; mt++) {
    int m = mt * 16 + r; if (m > 48) m = 48;
    int oy = m / 7, ox = m % 7;
    f32x4 acc = {0.f, 0.f, 0.f, 0.f};
    #pragma unroll
    for (int ks = 0; ks < 18; ks++) {
      int kyx = ks >> 1;
      int ky = kyx / 3, kx = kyx % 3;
      int ic0 = (ks & 1) * 32 + q * 8;
      int ai = ((oy + ky) * 9 + ox + kx) * 64 + ic0;  // 16B aligned
      short8v av = *(const short8v*)&lds[ai];
      acc = __builtin_amdgcn_mfma_f32_16x16x32_bf16(av, bfr[ks], acc, 0, 0, 0);
    }
    #pragma unroll
    for (int reg = 0; reg < 4; reg++) {
      int pos = mt * 16 + q * 4 + reg;
      if (pos < 49)
        out[(size_t)fr * 3136 + n * 49 + pos] = fmaxf(acc[reg] + bn, 0.f);
    }
  }
}

// ---------------- generic tiled f32 GEMM: C[m,n] = post(preA @ W + bias) ----------------
// PRE: 0 none, 1 gelu on A.  POST: 0 none, 1 tanh, 2 gelu then + res (residual)
template<int PRE, int POST>
__global__ __launch_bounds__(256) void gemm_k(const float* __restrict__ A,
    const float* __restrict__ W, const float* __restrict__ bias,
    const float* __restrict__ res, float* __restrict__ C,
    int M, int K, int N, int ldc) {
  __shared__ float As[16][68];
  __shared__ float Ws[16][64];
  int tid = threadIdx.x;
  int bm = blockIdx.y * 64, bn = blockIdx.x * 64;
  int tx = tid & 15, ty = tid >> 4;
  float acc[4][4] = {};
  for (int k0 = 0; k0 < K; k0 += 16) {
    #pragma unroll
    for (int i = 0; i < 4; i++) {
      int idx = tid + i * 256;
      int m = idx >> 4, kk = idx & 15;
      float a = A[(size_t)(bm + m) * K + k0 + kk];
      if (PRE == 1) a = gelu_f(a);
      As[kk][m] = a;
    }
    #pragma unroll
    for (int i = 0; i < 4; i++) {
      int idx = tid + i * 256;
      int kk = idx >> 6, n = idx & 63;
      Ws[kk][n] = (bn + n < N) ? W[(size_t)(k0 + kk) * N + bn + n] : 0.f;
    }
    __syncthreads();
    #pragma unroll
    for (int kk = 0; kk < 16; kk++) {
      float a0 = As[kk][ty * 4 + 0], a1 = As[kk][ty * 4 + 1];
      float a2 = As[kk][ty * 4 + 2], a3 = As[kk][ty * 4 + 3];
      float b0 = Ws[kk][tx * 4 + 0], b1 = Ws[kk][tx * 4 + 1];
      float b2 = Ws[kk][tx * 4 + 2], b3 = Ws[kk][tx * 4 + 3];
      acc[0][0] = fmaf(a0, b0, acc[0][0]); acc[0][1] = fmaf(a0, b1, acc[0][1]);
      acc[0][2] = fmaf(a0, b2, acc[0][2]); acc[0][3] = fmaf(a0, b3, acc[0][3]);
      acc[1][0] = fmaf(a1, b0, acc[1][0]); acc[1][1] = fmaf(a1, b1, acc[1][1]);
      acc[1][2] = fmaf(a1, b2, acc[1][2]); acc[1][3] = fmaf(a1, b3, acc[1][3]);
      acc[2][0] = fmaf(a2, b0, acc[2][0]); acc[2][1] = fmaf(a2, b1, acc[2][1]);
      acc[2][2] = fmaf(a2, b2, acc[2][2]); acc[2][3] = fmaf(a2, b3, acc[2][3]);
      acc[3][0] = fmaf(a3, b0, acc[3][0]); acc[3][1] = fmaf(a3, b1, acc[3][1]);
      acc[3][2] = fmaf(a3, b2, acc[3][2]); acc[3][3] = fmaf(a3, b3, acc[3][3]);
    }
    __syncthreads();
  }
  #pragma unroll
  for (int i = 0; i < 4; i++) {
    #pragma unroll
    for (int j = 0; j < 4; j++) {
      int m = bm + ty * 4 + i, n = bn + tx * 4 + j;
      if (n < N) {
        float v = acc[i][j] + (bias ? bias[n] : 0.f);
        if (POST == 1) v = tanhf(v);
        if (POST == 2) v = gelu_f(v) + res[(size_t)m * ldc + n];
        C[(size_t)m * ldc + n] = v;
      }
    }
  }
}

// ---------------- action + rtg embeddings into uin[:,128:384] ----------------
__global__ __launch_bounds__(256) void embed_k(const int* __restrict__ actions,
    const float* __restrict__ rtgs, const float* __restrict__ act_emb,
    const float* __restrict__ ret_w, const float* __restrict__ ret_b,
    float* __restrict__ uin) {
  int f = blockIdx.x;
  int b = f >> 7, s = f & 127;
  int e = threadIdx.x;
  if (e < 128) {
    int a = actions[b * Tq + s];
    uin[(size_t)f * 384 + 128 + e] = tanhf(act_emb[a * NEq + e]);
  } else {
    int ee = e - 128;
    uin[(size_t)f * 384 + 256 + ee] =
        tanhf(fmaf(rtgs[b * Tq + s], ret_w[ee], ret_b[ee]));
  }
}

// ---------------- S4 kernel generation: Kt[layer][l][h] ----------------
__global__ __launch_bounds__(128) void s4k_gen(const float* __restrict__ log_dt,
    const float* __restrict__ A_re, const float* __restrict__ A_im,
    const float* __restrict__ C_re, const float* __restrict__ C_im,
    float* __restrict__ Kt) {
  int lh = blockIdx.x;
  int l = threadIdx.x;
  float fl = (float)l;
  float dt = expf(log_dt[lh]);
  const float* Ar = A_re + (size_t)lh * Nq;
  const float* Ai = A_im + (size_t)lh * Nq;
  const float* Cr = C_re + (size_t)lh * Nq;
  const float* Ci = C_im + (size_t)lh * Nq;
  float acc = 0.f;
  for (int n = 0; n < Nq; n++) {
    float ar = Ar[n], ai = Ai[n];
    float al = dt * ar, be = dt * ai;
    float er = expf(al);
    float zr = er * cosf(be) - 1.0f;
    float zi = er * sinf(be);
    float den = 1.0f / (ar * ar + ai * ai);
    float wr = (zr * ar + zi * ai) * den;
    float wi = (zi * ar - zr * ai) * den;
    float cr = Cr[n] * wr - Ci[n] * wi;
    float ci = Cr[n] * wi + Ci[n] * wr;
    float e2 = expf(al * fl);
    float vr = e2 * cosf(be * fl);
    float vi = e2 * sinf(be * fl);
    acc += cr * vr - ci * vi;
  }
  int layer = lh >> 9, h = lh & 511;
  Kt[((size_t)layer * Sq + l) * Hq + h] = 2.0f * acc;
}

// ---------------- layernorm over H=512, one wave per row ----------------
__global__ __launch_bounds__(64) void ln_k(const float* __restrict__ y,
    const float* __restrict__ g, const float* __restrict__ b, float* __restrict__ r) {
  int row = blockIdx.x;
  const float* x = y + (size_t)row * Hq;
  int lane = threadIdx.x;
  float v[8], s = 0.f, s2 = 0.f;
  #pragma unroll
  for (int j = 0; j < 8; j++) {
    v[j] = x[lane + j * 64];
    s += v[j];
    s2 += v[j] * v[j];
  }
  #pragma unroll
  for (int o = 32; o >= 1; o >>= 1) {
    s += __shfl_xor(s, o);
    s2 += __shfl_xor(s2, o);
  }
  float mu = s * (1.f / Hq);
  float var = s2 * (1.f / Hq) - mu * mu;
  float inv = rsqrtf(var + 1e-5f);
  float* out = r + (size_t)row * Hq;
  #pragma unroll
  for (int j = 0; j < 8; j++) {
    int h = lane + j * 64;
    out[h] = (v[j] - mu) * inv * g[h] + b[h];
  }
}

// ---------------- causal conv along sequence ----------------
__global__ __launch_bounds__(512) void sconv_k(const float* __restrict__ r,
    const float* __restrict__ Kt, const float* __restrict__ D, float* __restrict__ c) {
  int s = blockIdx.x, b = blockIdx.y;
  int h = threadIdx.x;
  const float* rb = r + (size_t)b * Sq * Hq + h;
  float acc = D[h] * rb[(size_t)s * Hq];
  for (int j = 0; j <= s; j++)
    acc = fmaf(Kt[(size_t)j * Hq + h], rb[(size_t)(s - j) * Hq], acc);
  c[((size_t)b * Sq + s) * Hq + h] = acc;
}

// ---------------- host ----------------
extern "C" void kernel_launch(void* const* d_in, const int* in_sizes, int n_in,
                              void* d_out, int out_size, void* d_ws, size_t ws_size,
                              hipStream_t stream) {
  const float* states  = (const float*)d_in[0];
  const int*   actions = (const int*)  d_in[1];
  const float* rtgs    = (const float*)d_in[2];
  const float* enc_w1  = (const float*)d_in[3];
  const float* enc_b1  = (const float*)d_in[4];
  const float* enc_w2  = (const float*)d_in[5];
  const float* enc_b2  = (const float*)d_in[6];
  const float* enc_w3  = (const float*)d_in[7];
  const float* enc_b3  = (const float*)d_in[8];
  const float* enc_lw  = (const float*)d_in[9];
  const float* enc_lb  = (const float*)d_in[10];
  const float* ret_w   = (const float*)d_in[11];
  const float* ret_b   = (const float*)d_in[12];
  const float* act_emb = (const float*)d_in[13];
  const float* proj_w  = (const float*)d_in[14];
  const float* proj_b  = (const float*)d_in[15];
  const float* pre_w   = (const float*)d_in[16];
  const float* pre_b   = (const float*)d_in[17];
  const float* ln_g    = (const float*)d_in[18];
  const float* ln_b    = (const float*)d_in[19];
  const float* log_dt  = (const float*)d_in[20];
  const float* A_re    = (const float*)d_in[21];
  const float* A_im    = (const float*)d_in[22];
  const float* C_re    = (const float*)d_in[23];
  const float* C_im    = (const float*)d_in[24];
  const float* Dp      = (const float*)d_in[25];
  const float* aft_w   = (const float*)d_in[26];
  const float* aft_b   = (const float*)d_in[27];
  const float* out_w   = (const float*)d_in[28];

  // workspace layout (~61 MB)
  u16* B1 = (u16*)d_ws;                 // 8192
  u16* B2 = B1 + 8192;                  // 32768
  u16* B3 = B2 + 32768;                 // 36864
  u16* o1 = B3 + 36864;                 // 1024*400*32 = 13,107,200 (bf16, [pos][oc])
  u16* o2 = o1 + 13107200;              // 1024*81*64  =  5,308,416 (bf16, [pos][oc])
  float* x3  = (float*)(o2 + 5308416);  // 1024*3136 f32, reference flatten order
  float* uin = x3 + 3211264;            // 1024*384
  float* u   = uin + 393216;            // 1024*512
  float* y   = u + 524288;
  float* r   = y + 524288;
  float* c   = r + 524288;
  float* Kt  = c + 524288;              // 4*128*512

  wprep_k<<<304, 256, 0, stream>>>(enc_w1, enc_w2, enc_w3, B1, B2, B3);
  conv1_mfma<<<1024, 256, 0, stream>>>(states, B1, enc_b1, o1);
  conv2_mfma<<<1024, 256, 0, stream>>>(o1, B2, enc_b2, o2);
  conv3_mfma<<<1024, 256, 0, stream>>>(o2, B3, enc_b3, x3);
  // se = tanh(x3 @ enc_lw + enc_lb) -> uin[:, 0:128]
  gemm_k<0, 1><<<dim3(2, 16), 256, 0, stream>>>(x3, enc_lw, enc_lb, nullptr, uin,
                                                1024, 3136, 128, 384);
  embed_k<<<1024, 256, 0, stream>>>(actions, rtgs, act_emb, ret_w, ret_b, uin);
  gemm_k<0, 0><<<dim3(8, 16), 256, 0, stream>>>(uin, proj_w, proj_b, nullptr, u,
                                                1024, 384, 512, 512);
  gemm_k<1, 0><<<dim3(8, 16), 256, 0, stream>>>(u, pre_w, pre_b, nullptr, y,
                                                1024, 512, 512, 512);
  s4k_gen<<<2048, 128, 0, stream>>>(log_dt, A_re, A_im, C_re, C_im, Kt);

  for (int i = 0; i < NLq; i++) {
    ln_k<<<1024, 64, 0, stream>>>(y, ln_g + i * Hq, ln_b + i * Hq, r);
    sconv_k<<<dim3(128, 8), 512, 0, stream>>>(r, Kt + (size_t)i * Sq * Hq,
                                              Dp + i * Hq, c);
    gemm_k<1, 2><<<dim3(8, 16), 256, 0, stream>>>(c, aft_w + (size_t)i * Hq * Hq,
                                                  aft_b + i * Hq, y, y,
                                                  1024, 512, 512, 512);
  }
  gemm_k<0, 0><<<dim3(1, 16), 256, 0, stream>>>(y, out_w, nullptr, nullptr,
                                                (float*)d_out, 1024, 512, Vq, Vq);
}

// Round 3
// 389.574 us; speedup vs baseline: 7.0239x; 2.5149x over previous
//
#include <hip/hip_runtime.h>

// ---------------- constants ----------------
#define Bq 8
#define Tq 129
#define Sq 128
#define Hq 512
#define Nq 64
#define NLq 4
#define NEq 128
#define Vq 18

typedef unsigned short u16;
typedef __attribute__((ext_vector_type(8))) short short8v;   // 8 bf16 (4 VGPRs), MFMA A/B frag
typedef __attribute__((ext_vector_type(4))) float f32x4;     // MFMA C/D frag

__device__ __forceinline__ float gelu_f(float x) {
  return 0.5f * x * (1.0f + erff(x * 0.70710678118654752f));
}

__device__ __forceinline__ u16 f2b(float x) {   // f32 -> bf16, round-to-nearest-even
  union { float f; unsigned int u; } v; v.f = x;
  unsigned int r = v.u + 0x7FFFu + ((v.u >> 16) & 1u);
  return (u16)(r >> 16);
}

// ---------------- conv weight prep: permute to bf16 B[k][n] ----------------
__global__ __launch_bounds__(256) void wprep_k(const float* __restrict__ w1,
    const float* __restrict__ w2, const float* __restrict__ w3,
    u16* __restrict__ B1, u16* __restrict__ B2, u16* __restrict__ B3) {
  int i = blockIdx.x * 256 + threadIdx.x;
  if (i < 8192) {                       // conv1: 256 x 32
    int k = i >> 5, n = i & 31;
    int ic = k >> 6, ky = (k >> 3) & 7, kx = k & 7;
    B1[i] = f2b(w1[((n * 4 + ic) * 8 + ky) * 8 + kx]);
  } else if (i < 8192 + 32768) {        // conv2: 512 x 64
    int j = i - 8192;
    int k = j >> 6, n = j & 63;
    int kyx = k >> 5, ic = k & 31, ky = kyx >> 2, kx = kyx & 3;
    B2[j] = f2b(w2[((n * 32 + ic) * 4 + ky) * 4 + kx]);
  } else if (i < 8192 + 32768 + 36864) { // conv3: 576 x 64
    int j = i - 40960;
    int k = j >> 6, n = j & 63;
    int ic = k & 63, kyx = k >> 6, ky = kyx / 3, kx = kyx % 3;
    B3[j] = f2b(w3[((n * 64 + ic) * 3 + ky) * 3 + kx]);
  }
}

// ---------------- dense weight prep: bf16 transpose W[k][n] -> Wt[n][k] ----------------
// 64x64 tiles via LDS. Matrices: enc(3136x128,98t) proj(384x512,48t) pre(512x512,64t)
// aft 4x(512x512,256t) out(512x18 -> [64][512] zero-padded, 8t). Total 474 blocks.
__global__ __launch_bounds__(256) void wtrans_k(const float* __restrict__ enc_lw,
    const float* __restrict__ proj_w, const float* __restrict__ pre_w,
    const float* __restrict__ aft_w, const float* __restrict__ out_w,
    u16* __restrict__ Wt_enc, u16* __restrict__ Wt_proj, u16* __restrict__ Wt_pre,
    u16* __restrict__ Wt_aft, u16* __restrict__ Wt_out) {
  __shared__ u16 T[64][65];
  int bid = blockIdx.x;
  const float* src; u16* dst; int K, N, kt, nt, t;
  if (bid < 98)       { t = bid;       src = enc_lw; dst = Wt_enc;  K = 3136; N = 128; kt = t >> 1; nt = t & 1; }
  else if (bid < 146) { t = bid - 98;  src = proj_w; dst = Wt_proj; K = 384;  N = 512; kt = t >> 3; nt = t & 7; }
  else if (bid < 210) { t = bid - 146; src = pre_w;  dst = Wt_pre;  K = 512;  N = 512; kt = t >> 3; nt = t & 7; }
  else if (bid < 466) { t = bid - 210; int L = t >> 6; t &= 63;
                        src = aft_w + (size_t)L * 262144; dst = Wt_aft + (size_t)L * 262144;
                        K = 512; N = 512; kt = t >> 3; nt = t & 7; }
  else                { t = bid - 466; src = out_w;  dst = Wt_out;  K = 512;  N = 18;  kt = t;      nt = 0; }
  int k0 = kt * 64, n0 = nt * 64;
  #pragma unroll
  for (int it = 0; it < 16; it++) {
    int idx = it * 256 + threadIdx.x;
    int rr = idx >> 6, cc = idx & 63;          // rr: k-off, cc: n-off
    float v = (n0 + cc < N) ? src[(size_t)(k0 + rr) * N + n0 + cc] : 0.f;
    T[cc][rr] = f2b(v);
  }
  __syncthreads();
  #pragma unroll
  for (int it = 0; it < 16; it++) {
    int idx = it * 256 + threadIdx.x;
    int rr = idx >> 6, cc = idx & 63;          // rr: n-off, cc: k-off
    dst[(size_t)(n0 + rr) * K + k0 + cc] = T[rr][cc];
  }
}

// ---------------- bf16 MFMA GEMM: C = epi(A @ Wt^T + bias) ----------------
// A: [M][K] bf16 (or f32 if AF32). Wt: [n][k] bf16. Tile 64x64, BK=32, 4 waves (2x2).
// EPI: 0 f32 (acc+bias), 1 bf16 tanh, 2 bf16 gelu, 3 f32 gelu+res
template<bool AF32, int EPI>
__global__ __launch_bounds__(256) void mgemm(const void* __restrict__ Av,
    const u16* __restrict__ Wt, const float* __restrict__ bias,
    const float* __restrict__ res, void* __restrict__ Cv,
    int M, int K, int N, int ldc) {
  __shared__ u16 As[64][40];   // [m][k] pad->80B stride: 2-way max on frag reads
  __shared__ u16 Bs[64][40];   // [n][k]
  int tid = threadIdx.x;
  int bn = blockIdx.x * 64, bm = blockIdx.y * 64;
  int lane = tid & 63, w = tid >> 6;
  int q = lane >> 4, r = lane & 15;
  int wm = (w >> 1) * 32, wn = (w & 1) * 32;
  int am = tid >> 2, ak = (tid & 3) * 8;       // staging coords (64 rows x 32 k)
  f32x4 acc[2][2] = {};
  for (int k0 = 0; k0 < K; k0 += 32) {
    if constexpr (AF32) {
      const float* A = (const float*)Av;
      const float* src = A + (size_t)(bm + am) * K + k0 + ak;
      float4 v0 = *(const float4*)src;
      float4 v1 = *(const float4*)(src + 4);
      ushort4 lo, hi;
      lo.x = f2b(v0.x); lo.y = f2b(v0.y); lo.z = f2b(v0.z); lo.w = f2b(v0.w);
      hi.x = f2b(v1.x); hi.y = f2b(v1.y); hi.z = f2b(v1.z); hi.w = f2b(v1.w);
      *(ushort4*)&As[am][ak] = lo;
      *(ushort4*)&As[am][ak + 4] = hi;
    } else {
      const u16* A = (const u16*)Av;
      *(short8v*)&As[am][ak] = *(const short8v*)(A + (size_t)(bm + am) * K + k0 + ak);
    }
    *(short8v*)&Bs[am][ak] = *(const short8v*)(Wt + (size_t)(bn + am) * K + k0 + ak);
    __syncthreads();
    short8v a0 = *(const short8v*)&As[wm + r][q * 8];
    short8v a1 = *(const short8v*)&As[wm + 16 + r][q * 8];
    short8v b0 = *(const short8v*)&Bs[wn + r][q * 8];
    short8v b1 = *(const short8v*)&Bs[wn + 16 + r][q * 8];
    acc[0][0] = __builtin_amdgcn_mfma_f32_16x16x32_bf16(a0, b0, acc[0][0], 0, 0, 0);
    acc[0][1] = __builtin_amdgcn_mfma_f32_16x16x32_bf16(a0, b1, acc[0][1], 0, 0, 0);
    acc[1][0] = __builtin_amdgcn_mfma_f32_16x16x32_bf16(a1, b0, acc[1][0], 0, 0, 0);
    acc[1][1] = __builtin_amdgcn_mfma_f32_16x16x32_bf16(a1, b1, acc[1][1], 0, 0, 0);
    __syncthreads();
  }
  #pragma unroll
  for (int ms = 0; ms < 2; ms++) {
    #pragma unroll
    for (int ns = 0; ns < 2; ns++) {
      #pragma unroll
      for (int reg = 0; reg < 4; reg++) {
        int m = bm + wm + ms * 16 + q * 4 + reg;
        int n = bn + wn + ns * 16 + r;
        if (n < N) {
          float v = acc[ms][ns][reg] + (bias ? bias[n] : 0.f);
          if (EPI == 0) ((float*)Cv)[(size_t)m * ldc + n] = v;
          if (EPI == 1) ((u16*)Cv)[(size_t)m * ldc + n] = f2b(tanhf(v));
          if (EPI == 2) ((u16*)Cv)[(size_t)m * ldc + n] = f2b(gelu_f(v));
          if (EPI == 3) ((float*)Cv)[(size_t)m * ldc + n] = gelu_f(v) + res[(size_t)m * ldc + n];
        }
      }
    }
  }
}

// ---------------- conv1 MFMA: [4,84,84]f32 -> [400 pos][32 oc]bf16, k8 s4, ReLU -------
__global__ __launch_bounds__(256) void conv1_mfma(const float* __restrict__ states,
    const u16* __restrict__ B1, const float* __restrict__ bias, u16* __restrict__ out) {
  __shared__ u16 lds[28224];            // [ic][84][84] bf16
  int fr = blockIdx.x;
  int b = fr >> 7, s = fr & 127;
  const float* in = states + (size_t)(b * Tq + s + 1) * 28224;
  int tid = threadIdx.x;
  #pragma unroll
  for (int it = 0; it < 28; it++) {
    int idx = tid + it * 256;
    if (idx < 7056) {
      float4 v = ((const float4*)in)[idx];
      ushort4 uv;
      uv.x = f2b(v.x); uv.y = f2b(v.y); uv.z = f2b(v.z); uv.w = f2b(v.w);
      *(ushort4*)&lds[idx * 4] = uv;
    }
  }
  int lane = tid & 63, w = tid >> 6;
  int q = lane >> 4, r = lane & 15;
  short8v bfr[2][8];
  #pragma unroll
  for (int nt = 0; nt < 2; nt++)
    #pragma unroll
    for (int ks = 0; ks < 8; ks++) {
      int k0 = ks * 32 + q * 8;
      #pragma unroll
      for (int j = 0; j < 8; j++)
        bfr[nt][ks][j] = (short)B1[(k0 + j) * 32 + nt * 16 + r];
    }
  __syncthreads();
  for (int mt = w; mt < 25; mt += 4) {
    int m = mt * 16 + r;
    int oy = m / 20, ox = m % 20;
    f32x4 acc0 = {0.f, 0.f, 0.f, 0.f}, acc1 = {0.f, 0.f, 0.f, 0.f};
    #pragma unroll
    for (int ks = 0; ks < 8; ks++) {
      int k0 = ks * 32 + q * 8;
      int ic = k0 >> 6, ky = (k0 >> 3) & 7;
      int ai = ic * 7056 + (oy * 4 + ky) * 84 + ox * 4;
      ushort4 lo = *(const ushort4*)&lds[ai];
      ushort4 hi = *(const ushort4*)&lds[ai + 4];
      short8v av;
      av[0] = (short)lo.x; av[1] = (short)lo.y; av[2] = (short)lo.z; av[3] = (short)lo.w;
      av[4] = (short)hi.x; av[5] = (short)hi.y; av[6] = (short)hi.z; av[7] = (short)hi.w;
      acc0 = __builtin_amdgcn_mfma_f32_16x16x32_bf16(av, bfr[0][ks], acc0, 0, 0, 0);
      acc1 = __builtin_amdgcn_mfma_f32_16x16x32_bf16(av, bfr[1][ks], acc1, 0, 0, 0);
    }
    #pragma unroll
    for (int reg = 0; reg < 4; reg++) {
      int pos = mt * 16 + q * 4 + reg;
      out[(size_t)fr * 12800 + pos * 32 + r]      = f2b(fmaxf(acc0[reg] + bias[r], 0.f));
      out[(size_t)fr * 12800 + pos * 32 + 16 + r] = f2b(fmaxf(acc1[reg] + bias[16 + r], 0.f));
    }
  }
}

// ---------------- conv2 MFMA: [20,20,32]bf16 -> [81 pos][64 oc]bf16, k4 s2, ReLU ------
__global__ __launch_bounds__(256) void conv2_mfma(const u16* __restrict__ in_,
    const u16* __restrict__ B2, const float* __restrict__ bias, u16* __restrict__ out) {
  __shared__ u16 lds[12800];
  int fr = blockIdx.x;
  int tid = threadIdx.x;
  const short8v* src = (const short8v*)(in_ + (size_t)fr * 12800);
  short8v* dst = (short8v*)lds;
  #pragma unroll
  for (int it = 0; it < 7; it++) {
    int idx = tid + it * 256;
    if (idx < 1600) dst[idx] = src[idx];
  }
  int lane = tid & 63, w = tid >> 6;
  int q = lane >> 4, r = lane & 15;
  int n = w * 16 + r;
  short8v bfr[16];
  #pragma unroll
  for (int ks = 0; ks < 16; ks++) {
    int k0 = ks * 32 + q * 8;
    #pragma unroll
    for (int j = 0; j < 8; j++)
      bfr[ks][j] = (short)B2[(k0 + j) * 64 + n];
  }
  __syncthreads();
  float bn = bias[n];
  #pragma unroll
  for (int mt = 0; mt < 6; mt++) {
    int m = mt * 16 + r; if (m > 80) m = 80;
    int oy = m / 9, ox = m % 9;
    f32x4 acc = {0.f, 0.f, 0.f, 0.f};
    #pragma unroll
    for (int ks = 0; ks < 16; ks++) {
      int ky = ks >> 2, kx = ks & 3;
      int ai = ((oy * 2 + ky) * 20 + ox * 2 + kx) * 32 + q * 8;
      short8v av = *(const short8v*)&lds[ai];
      acc = __builtin_amdgcn_mfma_f32_16x16x32_bf16(av, bfr[ks], acc, 0, 0, 0);
    }
    #pragma unroll
    for (int reg = 0; reg < 4; reg++) {
      int pos = mt * 16 + q * 4 + reg;
      if (pos < 81)
        out[(size_t)fr * 5184 + pos * 64 + n] = f2b(fmaxf(acc[reg] + bn, 0.f));
    }
  }
}

// ---------------- conv3 MFMA: [9,9,64]bf16 -> bf16 [oc=64][49 pos], k3 s1, ReLU -------
__global__ __launch_bounds__(256) void conv3_mfma(const u16* __restrict__ in_,
    const u16* __restrict__ B3, const float* __restrict__ bias, u16* __restrict__ out) {
  __shared__ u16 lds[5184];
  int fr = blockIdx.x;
  int tid = threadIdx.x;
  const short8v* src = (const short8v*)(in_ + (size_t)fr * 5184);
  short8v* dst = (short8v*)lds;
  #pragma unroll
  for (int it = 0; it < 3; it++) {
    int idx = tid + it * 256;
    if (idx < 648) dst[idx] = src[idx];
  }
  int lane = tid & 63, w = tid >> 6;
  int q = lane >> 4, r = lane & 15;
  int n = w * 16 + r;
  short8v bfr[18];
  #pragma unroll
  for (int ks = 0; ks < 18; ks++) {
    int k0 = ks * 32 + q * 8;
    #pragma unroll
    for (int j = 0; j < 8; j++)
      bfr[ks][j] = (short)B3[(k0 + j) * 64 + n];
  }
  __syncthreads();
  float bn = bias[n];
  #pragma unroll
  for (int mt = 0; mt < 4; mt++) {
    int m = mt * 16 + r; if (m > 48) m = 48;
    int oy = m / 7, ox = m % 7;
    f32x4 acc = {0.f, 0.f, 0.f, 0.f};
    #pragma unroll
    for (int ks = 0; ks < 18; ks++) {
      int kyx = ks >> 1;
      int ky = kyx / 3, kx = kyx % 3;
      int ic0 = (ks & 1) * 32 + q * 8;
      int ai = ((oy + ky) * 9 + ox + kx) * 64 + ic0;
      short8v av = *(const short8v*)&lds[ai];
      acc = __builtin_amdgcn_mfma_f32_16x16x32_bf16(av, bfr[ks], acc, 0, 0, 0);
    }
    #pragma unroll
    for (int reg = 0; reg < 4; reg++) {
      int pos = mt * 16 + q * 4 + reg;
      if (pos < 49)
        out[(size_t)fr * 3136 + n * 49 + pos] = f2b(fmaxf(acc[reg] + bn, 0.f));
    }
  }
}

// ---------------- action + rtg embeddings into uin[:,128:384] (bf16) ----------------
__global__ __launch_bounds__(256) void embed_k(const int* __restrict__ actions,
    const float* __restrict__ rtgs, const float* __restrict__ act_emb,
    const float* __restrict__ ret_w, const float* __restrict__ ret_b,
    u16* __restrict__ uin) {
  int f = blockIdx.x;
  int b = f >> 7, s = f & 127;
  int e = threadIdx.x;
  if (e < 128) {
    int a = actions[b * Tq + s];
    uin[(size_t)f * 384 + 128 + e] = f2b(tanhf(act_emb[a * NEq + e]));
  } else {
    int ee = e - 128;
    uin[(size_t)f * 384 + 256 + ee] =
        f2b(tanhf(fmaf(rtgs[b * Tq + s], ret_w[ee], ret_b[ee])));
  }
}

// ---------------- S4 kernel gen via complex-power recurrence: Kt[layer][l][h] ----------
// block = (layer,h), 64 threads = n. z_{l+1} = z_l * w; K[l] = 2*sum_n Re(Ceff*z_l).
__global__ __launch_bounds__(64) void s4k_gen(const float* __restrict__ log_dt,
    const float* __restrict__ A_re, const float* __restrict__ A_im,
    const float* __restrict__ C_re, const float* __restrict__ C_im,
    float* __restrict__ Kt) {
  __shared__ float con[64][129];
  int lh = blockIdx.x;            // layer*512 + h
  int n = threadIdx.x;            // 0..63
  float dt = expf(log_dt[lh]);
  float ar = A_re[(size_t)lh * Nq + n], ai = A_im[(size_t)lh * Nq + n];
  float al = dt * ar, be = dt * ai;
  float er = expf(al);
  float wr = er * cosf(be), wi = er * sinf(be);   // w = exp(dt*A)
  float zr = wr - 1.0f, zi = wi;                  // w - 1
  float den = 1.0f / (ar * ar + ai * ai);
  float tr = (zr * ar + zi * ai) * den, ti = (zi * ar - zr * ai) * den;  // (w-1)/A
  float Cr = C_re[(size_t)lh * Nq + n], Ci = C_im[(size_t)lh * Nq + n];
  float cr = Cr * tr - Ci * ti, ci = Cr * ti + Ci * tr;                  // Ceff
  float curr = 1.0f, curi = 0.0f;                 // z = w^l
  for (int l = 0; l < Sq; l++) {
    con[n][l] = cr * curr - ci * curi;            // Re(Ceff * z)
    float nr = curr * wr - curi * wi;
    curi = curr * wi + curi * wr;
    curr = nr;
  }
  __syncthreads();
  int layer = lh >> 9, h = lh & 511;
  #pragma unroll
  for (int li = n; li < Sq; li += 64) {
    float s = 0.f;
    for (int j = 0; j < 64; j++) s += con[j][li];
    Kt[((size_t)layer * Sq + li) * Hq + h] = 2.0f * s;
  }
}

// ---------------- layernorm over H=512, one wave per row ----------------
__global__ __launch_bounds__(64) void ln_k(const float* __restrict__ y,
    const float* __restrict__ g, const float* __restrict__ b, float* __restrict__ r) {
  int row = blockIdx.x;
  const float* x = y + (size_t)row * Hq;
  int lane = threadIdx.x;
  float v[8], s = 0.f, s2 = 0.f;
  #pragma unroll
  for (int j = 0; j < 8; j++) {
    v[j] = x[lane + j * 64];
    s += v[j];
    s2 += v[j] * v[j];
  }
  #pragma unroll
  for (int o = 32; o >= 1; o >>= 1) {
    s += __shfl_xor(s, o);
    s2 += __shfl_xor(s2, o);
  }
  float mu = s * (1.f / Hq);
  float var = s2 * (1.f / Hq) - mu * mu;
  float inv = rsqrtf(var + 1e-5f);
  float* out = r + (size_t)row * Hq;
  #pragma unroll
  for (int j = 0; j < 8; j++) {
    int h = lane + j * 64;
    out[h] = (v[j] - mu) * inv * g[h] + b[h];
  }
}

// ---------------- causal seq conv + gelu -> bf16 ----------------
__global__ __launch_bounds__(512) void sconv_k(const float* __restrict__ r,
    const float* __restrict__ Kt, const float* __restrict__ D, u16* __restrict__ cact) {
  int s = blockIdx.x, b = blockIdx.y;
  int h = threadIdx.x;
  const float* rb = r + (size_t)b * Sq * Hq + h;
  float acc = D[h] * rb[(size_t)s * Hq];
  for (int j = 0; j <= s; j++)
    acc = fmaf(Kt[(size_t)j * Hq + h], rb[(size_t)(s - j) * Hq], acc);
  cact[((size_t)b * Sq + s) * Hq + h] = f2b(gelu_f(acc));
}

// ---------------- host ----------------
extern "C" void kernel_launch(void* const* d_in, const int* in_sizes, int n_in,
                              void* d_out, int out_size, void* d_ws, size_t ws_size,
                              hipStream_t stream) {
  const float* states  = (const float*)d_in[0];
  const int*   actions = (const int*)  d_in[1];
  const float* rtgs    = (const float*)d_in[2];
  const float* enc_w1  = (const float*)d_in[3];
  const float* enc_b1  = (const float*)d_in[4];
  const float* enc_w2  = (const float*)d_in[5];
  const float* enc_b2  = (const float*)d_in[6];
  const float* enc_w3  = (const float*)d_in[7];
  const float* enc_b3  = (const float*)d_in[8];
  const float* enc_lw  = (const float*)d_in[9];
  const float* enc_lb  = (const float*)d_in[10];
  const float* ret_w   = (const float*)d_in[11];
  const float* ret_b   = (const float*)d_in[12];
  const float* act_emb = (const float*)d_in[13];
  const float* proj_w  = (const float*)d_in[14];
  const float* proj_b  = (const float*)d_in[15];
  const float* pre_w   = (const float*)d_in[16];
  const float* pre_b   = (const float*)d_in[17];
  const float* ln_g    = (const float*)d_in[18];
  const float* ln_b    = (const float*)d_in[19];
  const float* log_dt  = (const float*)d_in[20];
  const float* A_re    = (const float*)d_in[21];
  const float* A_im    = (const float*)d_in[22];
  const float* C_re    = (const float*)d_in[23];
  const float* C_im    = (const float*)d_in[24];
  const float* Dp      = (const float*)d_in[25];
  const float* aft_w   = (const float*)d_in[26];
  const float* aft_b   = (const float*)d_in[27];
  const float* out_w   = (const float*)d_in[28];

  // workspace layout (~55 MB), all regions 16B-aligned
  u16* Wt_enc  = (u16*)d_ws;            // 128*3136 = 401,408
  u16* Wt_proj = Wt_enc + 401408;       // 512*384  = 196,608
  u16* Wt_pre  = Wt_proj + 196608;      // 512*512  = 262,144
  u16* Wt_aft  = Wt_pre + 262144;       // 4*512*512= 1,048,576
  u16* Wt_out  = Wt_aft + 1048576;      // 64*512   = 32,768
  u16* B1 = Wt_out + 32768;             // 8,192
  u16* B2 = B1 + 8192;                  // 32,768
  u16* B3 = B2 + 32768;                 // 36,864
  u16* o1 = B3 + 36864;                 // 1024*400*32 = 13,107,200
  u16* o2 = o1 + 13107200;              // 1024*81*64  =  5,308,416
  u16* x3b  = o2 + 5308416;             // 1024*3136   =  3,211,264
  u16* uin  = x3b + 3211264;            // 1024*384
  u16* uact = uin + 393216;             // 1024*512
  u16* cact = uact + 524288;            // 1024*512
  float* y    = (float*)(cact + 524288);// 1024*512 f32
  float* rbuf = y + 524288;             // 1024*512 f32
  float* Kt   = rbuf + 524288;          // 4*128*512 f32

  wprep_k<<<304, 256, 0, stream>>>(enc_w1, enc_w2, enc_w3, B1, B2, B3);
  wtrans_k<<<474, 256, 0, stream>>>(enc_lw, proj_w, pre_w, aft_w, out_w,
                                    Wt_enc, Wt_proj, Wt_pre, Wt_aft, Wt_out);
  conv1_mfma<<<1024, 256, 0, stream>>>(states, B1, enc_b1, o1);
  conv2_mfma<<<1024, 256, 0, stream>>>(o1, B2, enc_b2, o2);
  conv3_mfma<<<1024, 256, 0, stream>>>(o2, B3, enc_b3, x3b);
  // se = tanh(x3 @ enc_lw + enc_lb) -> uin[:, 0:128] (bf16)
  mgemm<false, 1><<<dim3(2, 16), 256, 0, stream>>>(x3b, Wt_enc, enc_lb, nullptr, uin,
                                                   1024, 3136, 128, 384);
  embed_k<<<1024, 256, 0, stream>>>(actions, rtgs, act_emb, ret_w, ret_b, uin);
  // uact = gelu(uin @ proj_w + proj_b)  (bf16)
  mgemm<false, 2><<<dim3(8, 16), 256, 0, stream>>>(uin, Wt_proj, proj_b, nullptr, uact,
                                                   1024, 384, 512, 512);
  // y = uact @ pre_w + pre_b  (f32)
  mgemm<false, 0><<<dim3(8, 16), 256, 0, stream>>>(uact, Wt_pre, pre_b, nullptr, y,
                                                   1024, 512, 512, 512);
  s4k_gen<<<2048, 64, 0, stream>>>(log_dt, A_re, A_im, C_re, C_im, Kt);

  for (int i = 0; i < NLq; i++) {
    ln_k<<<1024, 64, 0, stream>>>(y, ln_g + i * Hq, ln_b + i * Hq, rbuf);
    sconv_k<<<dim3(128, 8), 512, 0, stream>>>(rbuf, Kt + (size_t)i * Sq * Hq,
                                              Dp + i * Hq, cact);
    // y = gelu(cact @ aft_w + aft_b) + y
    mgemm<false, 3><<<dim3(8, 16), 256, 0, stream>>>(cact, Wt_aft + (size_t)i * Hq * Hq,
                                                     aft_b + i * Hq, y, y,
                                                     1024, 512, 512, 512);
  }
  // logits = y @ out_w  (f32, no bias)
  mgemm<true, 0><<<dim3(1, 16), 256, 0, stream>>>(y, Wt_out, nullptr, nullptr,
                                                  (float*)d_out, 1024, 512, Vq, Vq);
}

// Round 4
// 268.029 us; speedup vs baseline: 10.2091x; 1.4535x over previous
//
#include <hip/hip_runtime.h>

// ---------------- constants ----------------
#define Bq 8
#define Tq 129
#define Sq 128
#define Hq 512
#define Nq 64
#define NLq 4
#define NEq 128
#define Vq 18

typedef unsigned short u16;
typedef unsigned int u32;
typedef __attribute__((ext_vector_type(8))) short short8v;   // 8 bf16 (4 VGPRs), MFMA A/B frag
typedef __attribute__((ext_vector_type(4))) float f32x4;     // MFMA C/D frag

__device__ __forceinline__ float gelu_f(float x) {
  return 0.5f * x * (1.0f + erff(x * 0.70710678118654752f));
}

__device__ __forceinline__ u16 f2b(float x) {   // f32 -> bf16, round-to-nearest-even
  union { float f; unsigned int u; } v; v.f = x;
  unsigned int r = v.u + 0x7FFFu + ((v.u >> 16) & 1u);
  return (u16)(r >> 16);
}

__device__ __forceinline__ float b2f_lo(u32 u) {  // low bf16 of packed pair -> f32
  union { unsigned int u; float f; } v; v.u = u << 16; return v.f;
}
__device__ __forceinline__ float b2f_hi(u32 u) {  // high bf16 -> f32
  union { unsigned int u; float f; } v; v.u = u & 0xffff0000u; return v.f;
}

// ---------------- conv weight prep: permute to bf16 Bt[n][k] (transposed) ----------------
__global__ __launch_bounds__(256) void wprep_k(const float* __restrict__ w1,
    const float* __restrict__ w2, const float* __restrict__ w3,
    u16* __restrict__ B1t, u16* __restrict__ B2t, u16* __restrict__ B3t) {
  int i = blockIdx.x * 256 + threadIdx.x;
  if (i < 8192) {                       // conv1: [n=32][k=256], k=ic*64+ky*8+kx
    int n = i >> 8, k = i & 255;
    int ic = k >> 6, ky = (k >> 3) & 7, kx = k & 7;
    B1t[i] = f2b(w1[((n * 4 + ic) * 8 + ky) * 8 + kx]);
  } else if (i < 8192 + 32768) {        // conv2: [n=64][k=512], k=(ky*4+kx)*32+ic
    int j = i - 8192;
    int n = j >> 9, k = j & 511;
    int kyx = k >> 5, ic = k & 31, ky = kyx >> 2, kx = kyx & 3;
    B2t[j] = f2b(w2[((n * 32 + ic) * 4 + ky) * 4 + kx]);
  } else if (i < 8192 + 32768 + 36864) { // conv3: [n=64][k=576], k=(ky*3+kx)*64+ic
    int j = i - 40960;
    int n = j / 576, k = j - n * 576;
    int ic = k & 63, kyx = k >> 6, ky = kyx / 3, kx = kyx % 3;
    B3t[j] = f2b(w3[((n * 64 + ic) * 3 + ky) * 3 + kx]);
  }
}

// ---------------- dense weight prep: bf16 transpose W[k][n] -> Wt[n][k] ----------------
__global__ __launch_bounds__(256) void wtrans_k(const float* __restrict__ enc_lw,
    const float* __restrict__ proj_w, const float* __restrict__ pre_w,
    const float* __restrict__ aft_w, const float* __restrict__ out_w,
    u16* __restrict__ Wt_enc, u16* __restrict__ Wt_proj, u16* __restrict__ Wt_pre,
    u16* __restrict__ Wt_aft, u16* __restrict__ Wt_out) {
  __shared__ u16 T[64][65];
  int bid = blockIdx.x;
  const float* src; u16* dst; int K, N, kt, nt, t;
  if (bid < 98)       { t = bid;       src = enc_lw; dst = Wt_enc;  K = 3136; N = 128; kt = t >> 1; nt = t & 1; }
  else if (bid < 146) { t = bid - 98;  src = proj_w; dst = Wt_proj; K = 384;  N = 512; kt = t >> 3; nt = t & 7; }
  else if (bid < 210) { t = bid - 146; src = pre_w;  dst = Wt_pre;  K = 512;  N = 512; kt = t >> 3; nt = t & 7; }
  else if (bid < 466) { t = bid - 210; int L = t >> 6; t &= 63;
                        src = aft_w + (size_t)L * 262144; dst = Wt_aft + (size_t)L * 262144;
                        K = 512; N = 512; kt = t >> 3; nt = t & 7; }
  else                { t = bid - 466; src = out_w;  dst = Wt_out;  K = 512;  N = 18;  kt = t;      nt = 0; }
  int k0 = kt * 64, n0 = nt * 64;
  #pragma unroll
  for (int it = 0; it < 16; it++) {
    int idx = it * 256 + threadIdx.x;
    int rr = idx >> 6, cc = idx & 63;
    float v = (n0 + cc < N) ? src[(size_t)(k0 + rr) * N + n0 + cc] : 0.f;
    T[cc][rr] = f2b(v);
  }
  __syncthreads();
  #pragma unroll
  for (int it = 0; it < 16; it++) {
    int idx = it * 256 + threadIdx.x;
    int rr = idx >> 6, cc = idx & 63;
    dst[(size_t)(n0 + rr) * K + k0 + cc] = T[rr][cc];
  }
}

// ---------------- bf16 MFMA GEMM: C = epi(A @ Wt^T + bias) ----------------
// A: [M][K] bf16 (or f32 if AF32). Wt: [n][k] bf16. Tile 64x64, BK=32, 4 waves (2x2).
// EPI: 0 f32 (acc+bias), 2 bf16 gelu, 3 f32 gelu+res
template<bool AF32, int EPI>
__global__ __launch_bounds__(256) void mgemm(const void* __restrict__ Av,
    const u16* __restrict__ Wt, const float* __restrict__ bias,
    const float* __restrict__ res, void* __restrict__ Cv,
    int M, int K, int N, int ldc) {
  __shared__ u16 As[64][40];
  __shared__ u16 Bs[64][40];
  int tid = threadIdx.x;
  int bn = blockIdx.x * 64, bm = blockIdx.y * 64;
  int lane = tid & 63, w = tid >> 6;
  int q = lane >> 4, r = lane & 15;
  int wm = (w >> 1) * 32, wn = (w & 1) * 32;
  int am = tid >> 2, ak = (tid & 3) * 8;
  f32x4 acc[2][2] = {};
  for (int k0 = 0; k0 < K; k0 += 32) {
    if constexpr (AF32) {
      const float* A = (const float*)Av;
      const float* src = A + (size_t)(bm + am) * K + k0 + ak;
      float4 v0 = *(const float4*)src;
      float4 v1 = *(const float4*)(src + 4);
      ushort4 lo, hi;
      lo.x = f2b(v0.x); lo.y = f2b(v0.y); lo.z = f2b(v0.z); lo.w = f2b(v0.w);
      hi.x = f2b(v1.x); hi.y = f2b(v1.y); hi.z = f2b(v1.z); hi.w = f2b(v1.w);
      *(ushort4*)&As[am][ak] = lo;
      *(ushort4*)&As[am][ak + 4] = hi;
    } else {
      const u16* A = (const u16*)Av;
      *(short8v*)&As[am][ak] = *(const short8v*)(A + (size_t)(bm + am) * K + k0 + ak);
    }
    *(short8v*)&Bs[am][ak] = *(const short8v*)(Wt + (size_t)(bn + am) * K + k0 + ak);
    __syncthreads();
    short8v a0 = *(const short8v*)&As[wm + r][q * 8];
    short8v a1 = *(const short8v*)&As[wm + 16 + r][q * 8];
    short8v b0 = *(const short8v*)&Bs[wn + r][q * 8];
    short8v b1 = *(const short8v*)&Bs[wn + 16 + r][q * 8];
    acc[0][0] = __builtin_amdgcn_mfma_f32_16x16x32_bf16(a0, b0, acc[0][0], 0, 0, 0);
    acc[0][1] = __builtin_amdgcn_mfma_f32_16x16x32_bf16(a0, b1, acc[0][1], 0, 0, 0);
    acc[1][0] = __builtin_amdgcn_mfma_f32_16x16x32_bf16(a1, b0, acc[1][0], 0, 0, 0);
    acc[1][1] = __builtin_amdgcn_mfma_f32_16x16x32_bf16(a1, b1, acc[1][1], 0, 0, 0);
    __syncthreads();
  }
  #pragma unroll
  for (int ms = 0; ms < 2; ms++) {
    #pragma unroll
    for (int ns = 0; ns < 2; ns++) {
      #pragma unroll
      for (int reg = 0; reg < 4; reg++) {
        int m = bm + wm + ms * 16 + q * 4 + reg;
        int n = bn + wn + ns * 16 + r;
        if (n < N) {
          float v = acc[ms][ns][reg] + (bias ? bias[n] : 0.f);
          if (EPI == 0) ((float*)Cv)[(size_t)m * ldc + n] = v;
          if (EPI == 2) ((u16*)Cv)[(size_t)m * ldc + n] = f2b(gelu_f(v));
          if (EPI == 3) ((float*)Cv)[(size_t)m * ldc + n] = gelu_f(v) + res[(size_t)m * ldc + n];
        }
      }
    }
  }
}

// ---------------- enc GEMM split-K: A[1024][3136]bf16 @ Wt[128][3136] -> Cp[7][1024][128] f32 ----
__global__ __launch_bounds__(256) void enc_gemm(const u16* __restrict__ A,
    const u16* __restrict__ Wt, float* __restrict__ Cp) {
  __shared__ u16 As[64][40];
  __shared__ u16 Bs[64][40];
  int tid = threadIdx.x;
  int bn = blockIdx.x * 64, bm = blockIdx.y * 64, kc = blockIdx.z;
  int lane = tid & 63, w = tid >> 6;
  int q = lane >> 4, r = lane & 15;
  int wm = (w >> 1) * 32, wn = (w & 1) * 32;
  int am = tid >> 2, ak = (tid & 3) * 8;
  f32x4 acc[2][2] = {};
  int kend = kc * 448 + 448;
  for (int k0 = kc * 448; k0 < kend; k0 += 32) {
    *(short8v*)&As[am][ak] = *(const short8v*)(A + (size_t)(bm + am) * 3136 + k0 + ak);
    *(short8v*)&Bs[am][ak] = *(const short8v*)(Wt + (size_t)(bn + am) * 3136 + k0 + ak);
    __syncthreads();
    short8v a0 = *(const short8v*)&As[wm + r][q * 8];
    short8v a1 = *(const short8v*)&As[wm + 16 + r][q * 8];
    short8v b0 = *(const short8v*)&Bs[wn + r][q * 8];
    short8v b1 = *(const short8v*)&Bs[wn + 16 + r][q * 8];
    acc[0][0] = __builtin_amdgcn_mfma_f32_16x16x32_bf16(a0, b0, acc[0][0], 0, 0, 0);
    acc[0][1] = __builtin_amdgcn_mfma_f32_16x16x32_bf16(a0, b1, acc[0][1], 0, 0, 0);
    acc[1][0] = __builtin_amdgcn_mfma_f32_16x16x32_bf16(a1, b0, acc[1][0], 0, 0, 0);
    acc[1][1] = __builtin_amdgcn_mfma_f32_16x16x32_bf16(a1, b1, acc[1][1], 0, 0, 0);
    __syncthreads();
  }
  #pragma unroll
  for (int ms = 0; ms < 2; ms++)
    #pragma unroll
    for (int ns = 0; ns < 2; ns++)
      #pragma unroll
      for (int reg = 0; reg < 4; reg++) {
        int m = bm + wm + ms * 16 + q * 4 + reg;
        int n = bn + wn + ns * 16 + r;
        Cp[(size_t)(kc * 1024 + m) * 128 + n] = acc[ms][ns][reg];
      }
}

// ---------------- enc reduce: sum 7 partials + bias + tanh -> uin[:,0:128] bf16 ----------
__global__ __launch_bounds__(256) void enc_red(const float* __restrict__ Cp,
    const float* __restrict__ bias, u16* __restrict__ uin) {
  int idx = blockIdx.x * 256 + threadIdx.x;   // < 131072
  int m = idx >> 7, n = idx & 127;
  float s = bias[n];
  #pragma unroll
  for (int kc = 0; kc < 7; kc++) s += Cp[(size_t)(kc * 1024 + m) * 128 + n];
  uin[(size_t)m * 384 + n] = f2b(tanhf(s));
}

// ---------------- conv1 MFMA: [4,84,84]f32 -> [400 pos][32 oc]bf16, k8 s4, ReLU -------
__global__ __launch_bounds__(256) void conv1_mfma(const float* __restrict__ states,
    const u16* __restrict__ B1t, const float* __restrict__ bias, u16* __restrict__ out) {
  __shared__ u16 lds[28224];            // [ic][84][84] bf16
  int fr = blockIdx.x;
  int b = fr >> 7, s = fr & 127;
  const float* in = states + (size_t)(b * Tq + s + 1) * 28224;
  int tid = threadIdx.x;
  #pragma unroll
  for (int it = 0; it < 28; it++) {
    int idx = tid + it * 256;
    if (idx < 7056) {
      float4 v = ((const float4*)in)[idx];
      ushort4 uv;
      uv.x = f2b(v.x); uv.y = f2b(v.y); uv.z = f2b(v.z); uv.w = f2b(v.w);
      *(ushort4*)&lds[idx * 4] = uv;
    }
  }
  int lane = tid & 63, w = tid >> 6;
  int q = lane >> 4, r = lane & 15;
  short8v bfr[2][8];
  #pragma unroll
  for (int nt = 0; nt < 2; nt++)
    #pragma unroll
    for (int ks = 0; ks < 8; ks++)
      bfr[nt][ks] = *(const short8v*)(B1t + (nt * 16 + r) * 256 + ks * 32 + q * 8);
  __syncthreads();
  for (int mt = w; mt < 25; mt += 4) {
    int m = mt * 16 + r;
    int oy = m / 20, ox = m % 20;
    f32x4 acc0 = {0.f, 0.f, 0.f, 0.f}, acc1 = {0.f, 0.f, 0.f, 0.f};
    #pragma unroll
    for (int ks = 0; ks < 8; ks++) {
      int k0 = ks * 32 + q * 8;
      int ic = k0 >> 6, ky = (k0 >> 3) & 7;
      int ai = ic * 7056 + (oy * 4 + ky) * 84 + ox * 4;
      ushort4 lo = *(const ushort4*)&lds[ai];
      ushort4 hi = *(const ushort4*)&lds[ai + 4];
      short8v av;
      av[0] = (short)lo.x; av[1] = (short)lo.y; av[2] = (short)lo.z; av[3] = (short)lo.w;
      av[4] = (short)hi.x; av[5] = (short)hi.y; av[6] = (short)hi.z; av[7] = (short)hi.w;
      acc0 = __builtin_amdgcn_mfma_f32_16x16x32_bf16(av, bfr[0][ks], acc0, 0, 0, 0);
      acc1 = __builtin_amdgcn_mfma_f32_16x16x32_bf16(av, bfr[1][ks], acc1, 0, 0, 0);
    }
    #pragma unroll
    for (int reg = 0; reg < 4; reg++) {
      int pos = mt * 16 + q * 4 + reg;
      out[(size_t)fr * 12800 + pos * 32 + r]      = f2b(fmaxf(acc0[reg] + bias[r], 0.f));
      out[(size_t)fr * 12800 + pos * 32 + 16 + r] = f2b(fmaxf(acc1[reg] + bias[16 + r], 0.f));
    }
  }
}

// ---------------- conv2 MFMA: [20,20,32]bf16 -> [81 pos][64 oc]bf16, k4 s2, ReLU ------
__global__ __launch_bounds__(256) void conv2_mfma(const u16* __restrict__ in_,
    const u16* __restrict__ B2t, const float* __restrict__ bias, u16* __restrict__ out) {
  __shared__ u16 lds[12800];
  int fr = blockIdx.x;
  int tid = threadIdx.x;
  const short8v* src = (const short8v*)(in_ + (size_t)fr * 12800);
  short8v* dst = (short8v*)lds;
  #pragma unroll
  for (int it = 0; it < 7; it++) {
    int idx = tid + it * 256;
    if (idx < 1600) dst[idx] = src[idx];
  }
  int lane = tid & 63, w = tid >> 6;
  int q = lane >> 4, r = lane & 15;
  int n = w * 16 + r;
  short8v bfr[16];
  #pragma unroll
  for (int ks = 0; ks < 16; ks++)
    bfr[ks] = *(const short8v*)(B2t + n * 512 + ks * 32 + q * 8);
  __syncthreads();
  float bn = bias[n];
  #pragma unroll
  for (int mt = 0; mt < 6; mt++) {
    int m = mt * 16 + r; if (m > 80) m = 80;
    int oy = m / 9, ox = m % 9;
    f32x4 acc = {0.f, 0.f, 0.f, 0.f};
    #pragma unroll
    for (int ks = 0; ks < 16; ks++) {
      int ky = ks >> 2, kx = ks & 3;
      int ai = ((oy * 2 + ky) * 20 + ox * 2 + kx) * 32 + q * 8;
      short8v av = *(const short8v*)&lds[ai];
      acc = __builtin_amdgcn_mfma_f32_16x16x32_bf16(av, bfr[ks], acc, 0, 0, 0);
    }
    #pragma unroll
    for (int reg = 0; reg < 4; reg++) {
      int pos = mt * 16 + q * 4 + reg;
      if (pos < 81)
        out[(size_t)fr * 5184 + pos * 64 + n] = f2b(fmaxf(acc[reg] + bn, 0.f));
    }
  }
}

// ---------------- conv3 MFMA: [9,9,64]bf16 -> bf16 [oc=64][49 pos], k3 s1, ReLU -------
__global__ __launch_bounds__(256) void conv3_mfma(const u16* __restrict__ in_,
    const u16* __restrict__ B3t, const float* __restrict__ bias, u16* __restrict__ out) {
  __shared__ u16 lds[5184];
  int fr = blockIdx.x;
  int tid = threadIdx.x;
  const short8v* src = (const short8v*)(in_ + (size_t)fr * 5184);
  short8v* dst = (short8v*)lds;
  #pragma unroll
  for (int it = 0; it < 3; it++) {
    int idx = tid + it * 256;
    if (idx < 648) dst[idx] = src[idx];
  }
  int lane = tid & 63, w = tid >> 6;
  int q = lane >> 4, r = lane & 15;
  int n = w * 16 + r;
  short8v bfr[18];
  #pragma unroll
  for (int ks = 0; ks < 18; ks++)
    bfr[ks] = *(const short8v*)(B3t + n * 576 + ks * 32 + q * 8);
  __syncthreads();
  float bn = bias[n];
  #pragma unroll
  for (int mt = 0; mt < 4; mt++) {
    int m = mt * 16 + r; if (m > 48) m = 48;
    int oy = m / 7, ox = m % 7;
    f32x4 acc = {0.f, 0.f, 0.f, 0.f};
    #pragma unroll
    for (int ks = 0; ks < 18; ks++) {
      int kyx = ks >> 1;
      int ky = kyx / 3, kx = kyx % 3;
      int ic0 = (ks & 1) * 32 + q * 8;
      int ai = ((oy + ky) * 9 + ox + kx) * 64 + ic0;
      short8v av = *(const short8v*)&lds[ai];
      acc = __builtin_amdgcn_mfma_f32_16x16x32_bf16(av, bfr[ks], acc, 0, 0, 0);
    }
    #pragma unroll
    for (int reg = 0; reg < 4; reg++) {
      int pos = mt * 16 + q * 4 + reg;
      if (pos < 49)
        out[(size_t)fr * 3136 + n * 49 + pos] = f2b(fmaxf(acc[reg] + bn, 0.f));
    }
  }
}

// ---------------- action + rtg embeddings into uin[:,128:384] (bf16) ----------------
__global__ __launch_bounds__(256) void embed_k(const int* __restrict__ actions,
    const float* __restrict__ rtgs, const float* __restrict__ act_emb,
    const float* __restrict__ ret_w, const float* __restrict__ ret_b,
    u16* __restrict__ uin) {
  int f = blockIdx.x;
  int b = f >> 7, s = f & 127;
  int e = threadIdx.x;
  if (e < 128) {
    int a = actions[b * Tq + s];
    uin[(size_t)f * 384 + 128 + e] = f2b(tanhf(act_emb[a * NEq + e]));
  } else {
    int ee = e - 128;
    uin[(size_t)f * 384 + 256 + ee] =
        f2b(tanhf(fmaf(rtgs[b * Tq + s], ret_w[ee], ret_b[ee])));
  }
}

// ---------------- S4 kernel gen via complex-power recurrence: Ktb[layer][l][h] bf16 ----
__global__ __launch_bounds__(64) void s4k_gen(const float* __restrict__ log_dt,
    const float* __restrict__ A_re, const float* __restrict__ A_im,
    const float* __restrict__ C_re, const float* __restrict__ C_im,
    u16* __restrict__ Ktb) {
  __shared__ float con[64][129];
  int lh = blockIdx.x;            // layer*512 + h
  int n = threadIdx.x;            // 0..63
  float dt = expf(log_dt[lh]);
  float ar = A_re[(size_t)lh * Nq + n], ai = A_im[(size_t)lh * Nq + n];
  float al = dt * ar, be = dt * ai;
  float er = expf(al);
  float wr = er * cosf(be), wi = er * sinf(be);   // w = exp(dt*A)
  float zr = wr - 1.0f, zi = wi;
  float den = 1.0f / (ar * ar + ai * ai);
  float tr = (zr * ar + zi * ai) * den, ti = (zi * ar - zr * ai) * den;
  float Cr = C_re[(size_t)lh * Nq + n], Ci = C_im[(size_t)lh * Nq + n];
  float cr = Cr * tr - Ci * ti, ci = Cr * ti + Ci * tr;
  float curr = 1.0f, curi = 0.0f;
  for (int l = 0; l < Sq; l++) {
    con[n][l] = cr * curr - ci * curi;
    float nr = curr * wr - curi * wi;
    curi = curr * wi + curi * wr;
    curr = nr;
  }
  __syncthreads();
  int layer = lh >> 9, h = lh & 511;
  #pragma unroll
  for (int li = n; li < Sq; li += 64) {
    float s = 0.f;
    for (int j = 0; j < 64; j++) s += con[j][li];
    Ktb[((size_t)layer * Sq + li) * Hq + h] = f2b(2.0f * s);
  }
}

// ---------------- layernorm over H=512, 4 rows/block, bf16 out ----------------
__global__ __launch_bounds__(256) void ln_k(const float* __restrict__ y,
    const float* __restrict__ g, const float* __restrict__ b, u16* __restrict__ r) {
  int row = blockIdx.x * 4 + (threadIdx.x >> 6);
  int lane = threadIdx.x & 63;
  const float* x = y + (size_t)row * Hq;
  float v[8], s = 0.f, s2 = 0.f;
  #pragma unroll
  for (int j = 0; j < 8; j++) {
    v[j] = x[lane + j * 64];
    s += v[j];
    s2 += v[j] * v[j];
  }
  #pragma unroll
  for (int o = 32; o >= 1; o >>= 1) {
    s += __shfl_xor(s, o);
    s2 += __shfl_xor(s2, o);
  }
  float mu = s * (1.f / Hq);
  float var = s2 * (1.f / Hq) - mu * mu;
  float inv = rsqrtf(var + 1e-5f);
  u16* out = r + (size_t)row * Hq;
  #pragma unroll
  for (int j = 0; j < 8; j++) {
    int h = lane + j * 64;
    out[h] = f2b((v[j] - mu) * inv * g[h] + b[h]);
  }
}

// ---------------- causal seq conv (bf16 in) + gelu -> bf16 ----------------
// block (s,b), 256 threads, thread t owns h-pair (2t, 2t+1) via packed uint loads.
__global__ __launch_bounds__(256) void sconv_k(const u16* __restrict__ r,
    const u16* __restrict__ Kt, const float* __restrict__ D, u16* __restrict__ cact) {
  int s = blockIdx.x, b = blockIdx.y;
  int t = threadIdx.x;
  const u32* rb = (const u32*)(r + (size_t)b * Sq * Hq) + t;  // row stride 256 u32
  const u32* kp = (const u32*)Kt + t;
  float2 d = ((const float2*)D)[t];
  u32 rs = rb[(size_t)s * 256];
  float acc0 = d.x * b2f_lo(rs), acc1 = d.y * b2f_hi(rs);
  int j = 0;
  for (; j + 4 <= s + 1; j += 4) {
    u32 k0 = kp[(size_t)(j + 0) * 256];
    u32 k1 = kp[(size_t)(j + 1) * 256];
    u32 k2 = kp[(size_t)(j + 2) * 256];
    u32 k3 = kp[(size_t)(j + 3) * 256];
    u32 r0 = rb[(size_t)(s - j - 0) * 256];
    u32 r1 = rb[(size_t)(s - j - 1) * 256];
    u32 r2 = rb[(size_t)(s - j - 2) * 256];
    u32 r3 = rb[(size_t)(s - j - 3) * 256];
    acc0 = fmaf(b2f_lo(k0), b2f_lo(r0), acc0); acc1 = fmaf(b2f_hi(k0), b2f_hi(r0), acc1);
    acc0 = fmaf(b2f_lo(k1), b2f_lo(r1), acc0); acc1 = fmaf(b2f_hi(k1), b2f_hi(r1), acc1);
    acc0 = fmaf(b2f_lo(k2), b2f_lo(r2), acc0); acc1 = fmaf(b2f_hi(k2), b2f_hi(r2), acc1);
    acc0 = fmaf(b2f_lo(k3), b2f_lo(r3), acc0); acc1 = fmaf(b2f_hi(k3), b2f_hi(r3), acc1);
  }
  for (; j <= s; j++) {
    u32 kv = kp[(size_t)j * 256];
    u32 rv = rb[(size_t)(s - j) * 256];
    acc0 = fmaf(b2f_lo(kv), b2f_lo(rv), acc0);
    acc1 = fmaf(b2f_hi(kv), b2f_hi(rv), acc1);
  }
  u32 outv = (u32)f2b(gelu_f(acc0)) | ((u32)f2b(gelu_f(acc1)) << 16);
  ((u32*)(cact + ((size_t)b * Sq + s) * Hq))[t] = outv;
}

// ---------------- host ----------------
extern "C" void kernel_launch(void* const* d_in, const int* in_sizes, int n_in,
                              void* d_out, int out_size, void* d_ws, size_t ws_size,
                              hipStream_t stream) {
  const float* states  = (const float*)d_in[0];
  const int*   actions = (const int*)  d_in[1];
  const float* rtgs    = (const float*)d_in[2];
  const float* enc_w1  = (const float*)d_in[3];
  const float* enc_b1  = (const float*)d_in[4];
  const float* enc_w2  = (const float*)d_in[5];
  const float* enc_b2  = (const float*)d_in[6];
  const float* enc_w3  = (const float*)d_in[7];
  const float* enc_b3  = (const float*)d_in[8];
  const float* enc_lw  = (const float*)d_in[9];
  const float* enc_lb  = (const float*)d_in[10];
  const float* ret_w   = (const float*)d_in[11];
  const float* ret_b   = (const float*)d_in[12];
  const float* act_emb = (const float*)d_in[13];
  const float* proj_w  = (const float*)d_in[14];
  const float* proj_b  = (const float*)d_in[15];
  const float* pre_w   = (const float*)d_in[16];
  const float* pre_b   = (const float*)d_in[17];
  const float* ln_g    = (const float*)d_in[18];
  const float* ln_b    = (const float*)d_in[19];
  const float* log_dt  = (const float*)d_in[20];
  const float* A_re    = (const float*)d_in[21];
  const float* A_im    = (const float*)d_in[22];
  const float* C_re    = (const float*)d_in[23];
  const float* C_im    = (const float*)d_in[24];
  const float* Dp      = (const float*)d_in[25];
  const float* aft_w   = (const float*)d_in[26];
  const float* aft_b   = (const float*)d_in[27];
  const float* out_w   = (const float*)d_in[28];

  // workspace layout (u16 units), all regions 16B aligned
  u16* Wt_enc  = (u16*)d_ws;            // 401,408
  u16* Wt_proj = Wt_enc + 401408;       // 196,608
  u16* Wt_pre  = Wt_proj + 196608;      // 262,144
  u16* Wt_aft  = Wt_pre + 262144;       // 1,048,576
  u16* Wt_out  = Wt_aft + 1048576;      // 32,768
  u16* B1t = Wt_out + 32768;            // 8,192
  u16* B2t = B1t + 8192;                // 32,768
  u16* B3t = B2t + 32768;               // 36,864
  u16* o1  = B3t + 36864;               // 13,107,200
  u16* o2  = o1 + 13107200;             // 5,308,416
  u16* x3b = o2 + 5308416;              // 3,211,264
  u16* uin = x3b + 3211264;             // 393,216
  u16* uact = uin + 393216;             // 524,288
  u16* cact = uact + 524288;            // 524,288
  u16* rb16 = cact + 524288;            // 524,288
  u16* Ktb  = rb16 + 524288;            // 262,144
  float* y  = (float*)(Ktb + 262144);   // 524,288 f32
  float* Cp = y + 524288;               // 917,504 f32 (7*1024*128)

  wprep_k<<<304, 256, 0, stream>>>(enc_w1, enc_w2, enc_w3, B1t, B2t, B3t);
  wtrans_k<<<474, 256, 0, stream>>>(enc_lw, proj_w, pre_w, aft_w, out_w,
                                    Wt_enc, Wt_proj, Wt_pre, Wt_aft, Wt_out);
  conv1_mfma<<<1024, 256, 0, stream>>>(states, B1t, enc_b1, o1);
  conv2_mfma<<<1024, 256, 0, stream>>>(o1, B2t, enc_b2, o2);
  conv3_mfma<<<1024, 256, 0, stream>>>(o2, B3t, enc_b3, x3b);
  // se = tanh(x3 @ enc_lw + enc_lb) -> uin[:, 0:128], via split-K
  enc_gemm<<<dim3(2, 16, 7), 256, 0, stream>>>(x3b, Wt_enc, Cp);
  enc_red<<<512, 256, 0, stream>>>(Cp, enc_lb, uin);
  embed_k<<<1024, 256, 0, stream>>>(actions, rtgs, act_emb, ret_w, ret_b, uin);
  // uact = gelu(uin @ proj_w + proj_b)  (bf16)
  mgemm<false, 2><<<dim3(8, 16), 256, 0, stream>>>(uin, Wt_proj, proj_b, nullptr, uact,
                                                   1024, 384, 512, 512);
  // y = uact @ pre_w + pre_b  (f32)
  mgemm<false, 0><<<dim3(8, 16), 256, 0, stream>>>(uact, Wt_pre, pre_b, nullptr, y,
                                                   1024, 512, 512, 512);
  s4k_gen<<<2048, 64, 0, stream>>>(log_dt, A_re, A_im, C_re, C_im, Ktb);

  for (int i = 0; i < NLq; i++) {
    ln_k<<<256, 256, 0, stream>>>(y, ln_g + i * Hq, ln_b + i * Hq, rb16);
    sconv_k<<<dim3(128, 8), 256, 0, stream>>>(rb16, Ktb + (size_t)i * Sq * Hq,
                                              Dp + i * Hq, cact);
    // y = gelu(cact @ aft_w + aft_b) + y
    mgemm<false, 3><<<dim3(8, 16), 256, 0, stream>>>(cact, Wt_aft + (size_t)i * Hq * Hq,
                                                     aft_b + i * Hq, y, y,
                                                     1024, 512, 512, 512);
  }
  // logits = y @ out_w  (f32, no bias)
  mgemm<true, 0><<<dim3(1, 16), 256, 0, stream>>>(y, Wt_out, nullptr, nullptr,
                                                  (float*)d_out, 1024, 512, Vq, Vq);
}

// Round 5
// 225.805 us; speedup vs baseline: 12.1181x; 1.1870x over previous
//
#include <hip/hip_runtime.h>

// ---------------- constants ----------------
#define Bq 8
#define Tq 129
#define Sq 128
#define Hq 512
#define Nq 64
#define NLq 4
#define NEq 128
#define Vq 18

typedef unsigned short u16;
typedef unsigned int u32;
typedef __attribute__((ext_vector_type(8))) short short8v;   // 8 bf16 (4 VGPRs), MFMA A/B frag
typedef __attribute__((ext_vector_type(4))) float f32x4;     // MFMA C/D frag

__device__ __forceinline__ float gelu_f(float x) {
  return 0.5f * x * (1.0f + erff(x * 0.70710678118654752f));
}

__device__ __forceinline__ u16 f2b(float x) {   // f32 -> bf16, round-to-nearest-even
  union { float f; unsigned int u; } v; v.f = x;
  unsigned int r = v.u + 0x7FFFu + ((v.u >> 16) & 1u);
  return (u16)(r >> 16);
}

__device__ __forceinline__ float b2f_lo(u32 u) {
  union { unsigned int u; float f; } v; v.u = u << 16; return v.f;
}
__device__ __forceinline__ float b2f_hi(u32 u) {
  union { unsigned int u; float f; } v; v.u = u & 0xffff0000u; return v.f;
}

// ---------------- merged weight prep ----------------
// blocks 0..473: dense transposes (f32 [k][n] -> bf16 [n][k])
// blocks 474..777: conv weight permutes to bf16 Bt[n][k]
__global__ __launch_bounds__(256) void prep_k(
    const float* __restrict__ enc_lw, const float* __restrict__ proj_w,
    const float* __restrict__ pre_w, const float* __restrict__ aft_w,
    const float* __restrict__ out_w,
    const float* __restrict__ w1, const float* __restrict__ w2,
    const float* __restrict__ w3,
    u16* __restrict__ Wt_enc, u16* __restrict__ Wt_proj, u16* __restrict__ Wt_pre,
    u16* __restrict__ Wt_aft, u16* __restrict__ Wt_out,
    u16* __restrict__ B1t, u16* __restrict__ B2t, u16* __restrict__ B3t) {
  __shared__ u16 T[64][65];
  int bid = blockIdx.x;
  if (bid >= 474) {  // conv permutes
    int i = (bid - 474) * 256 + threadIdx.x;
    if (i < 8192) {                       // conv1: [n=32][k=256], k=ic*64+ky*8+kx
      int n = i >> 8, k = i & 255;
      int ic = k >> 6, ky = (k >> 3) & 7, kx = k & 7;
      B1t[i] = f2b(w1[((n * 4 + ic) * 8 + ky) * 8 + kx]);
    } else if (i < 8192 + 32768) {        // conv2: [n=64][k=512], k=(ky*4+kx)*32+ic
      int j = i - 8192;
      int n = j >> 9, k = j & 511;
      int kyx = k >> 5, ic = k & 31, ky = kyx >> 2, kx = kyx & 3;
      B2t[j] = f2b(w2[((n * 32 + ic) * 4 + ky) * 4 + kx]);
    } else if (i < 8192 + 32768 + 36864) { // conv3: [n=64][k=576], k=(ky*3+kx)*64+ic
      int j = i - 40960;
      int n = j / 576, k = j - n * 576;
      int ic = k & 63, kyx = k >> 6, ky = kyx / 3, kx = kyx % 3;
      B3t[j] = f2b(w3[((n * 64 + ic) * 3 + ky) * 3 + kx]);
    }
    return;
  }
  const float* src; u16* dst; int K, N, kt, nt, t;
  if (bid < 98)       { t = bid;       src = enc_lw; dst = Wt_enc;  K = 3136; N = 128; kt = t >> 1; nt = t & 1; }
  else if (bid < 146) { t = bid - 98;  src = proj_w; dst = Wt_proj; K = 384;  N = 512; kt = t >> 3; nt = t & 7; }
  else if (bid < 210) { t = bid - 146; src = pre_w;  dst = Wt_pre;  K = 512;  N = 512; kt = t >> 3; nt = t & 7; }
  else if (bid < 466) { t = bid - 210; int L = t >> 6; t &= 63;
                        src = aft_w + (size_t)L * 262144; dst = Wt_aft + (size_t)L * 262144;
                        K = 512; N = 512; kt = t >> 3; nt = t & 7; }
  else                { t = bid - 466; src = out_w;  dst = Wt_out;  K = 512;  N = 18;  kt = t;      nt = 0; }
  int k0 = kt * 64, n0 = nt * 64;
  #pragma unroll
  for (int it = 0; it < 16; it++) {
    int idx = it * 256 + threadIdx.x;
    int rr = idx >> 6, cc = idx & 63;
    float v = (n0 + cc < N) ? src[(size_t)(k0 + rr) * N + n0 + cc] : 0.f;
    T[cc][rr] = f2b(v);
  }
  __syncthreads();
  #pragma unroll
  for (int it = 0; it < 16; it++) {
    int idx = it * 256 + threadIdx.x;
    int rr = idx >> 6, cc = idx & 63;
    dst[(size_t)(n0 + rr) * K + k0 + cc] = T[rr][cc];
  }
}

// ---------------- bf16 MFMA GEMM: C = epi(A @ Wt^T + bias), BK=128 ----------------
// A: [M][K] bf16 (or f32 if AF32). Wt: [n][k] bf16. Tile 64x64, 4 waves (2x2).
// EPI: 0 f32 (acc+bias), 2 bf16 gelu, 3 f32 gelu+res. K must be mult of 128.
template<bool AF32, int EPI>
__global__ __launch_bounds__(256) void mgemm(const void* __restrict__ Av,
    const u16* __restrict__ Wt, const float* __restrict__ bias,
    const float* __restrict__ res, void* __restrict__ Cv,
    int M, int K, int N, int ldc) {
  __shared__ u16 As[4][64][40];
  __shared__ u16 Bs[4][64][40];
  int tid = threadIdx.x;
  int bn = blockIdx.x * 64, bm = blockIdx.y * 64;
  int lane = tid & 63, w = tid >> 6;
  int q = lane >> 4, r = lane & 15;
  int wm = (w >> 1) * 32, wn = (w & 1) * 32;
  int am = tid >> 2, ak0 = (tid & 3) * 8;
  f32x4 acc[2][2] = {};
  for (int k0 = 0; k0 < K; k0 += 128) {
    #pragma unroll
    for (int st = 0; st < 4; st++) {
      int kk = k0 + st * 32 + ak0;
      if constexpr (AF32) {
        const float* A = (const float*)Av;
        const float* src = A + (size_t)(bm + am) * K + kk;
        float4 v0 = *(const float4*)src;
        float4 v1 = *(const float4*)(src + 4);
        ushort4 lo, hi;
        lo.x = f2b(v0.x); lo.y = f2b(v0.y); lo.z = f2b(v0.z); lo.w = f2b(v0.w);
        hi.x = f2b(v1.x); hi.y = f2b(v1.y); hi.z = f2b(v1.z); hi.w = f2b(v1.w);
        *(ushort4*)&As[st][am][ak0] = lo;
        *(ushort4*)&As[st][am][ak0 + 4] = hi;
      } else {
        *(short8v*)&As[st][am][ak0] =
            *(const short8v*)((const u16*)Av + (size_t)(bm + am) * K + kk);
      }
      *(short8v*)&Bs[st][am][ak0] = *(const short8v*)(Wt + (size_t)(bn + am) * K + kk);
    }
    __syncthreads();
    #pragma unroll
    for (int st = 0; st < 4; st++) {
      short8v a0 = *(const short8v*)&As[st][wm + r][q * 8];
      short8v a1 = *(const short8v*)&As[st][wm + 16 + r][q * 8];
      short8v b0 = *(const short8v*)&Bs[st][wn + r][q * 8];
      short8v b1 = *(const short8v*)&Bs[st][wn + 16 + r][q * 8];
      acc[0][0] = __builtin_amdgcn_mfma_f32_16x16x32_bf16(a0, b0, acc[0][0], 0, 0, 0);
      acc[0][1] = __builtin_amdgcn_mfma_f32_16x16x32_bf16(a0, b1, acc[0][1], 0, 0, 0);
      acc[1][0] = __builtin_amdgcn_mfma_f32_16x16x32_bf16(a1, b0, acc[1][0], 0, 0, 0);
      acc[1][1] = __builtin_amdgcn_mfma_f32_16x16x32_bf16(a1, b1, acc[1][1], 0, 0, 0);
    }
    __syncthreads();
  }
  #pragma unroll
  for (int ms = 0; ms < 2; ms++) {
    #pragma unroll
    for (int ns = 0; ns < 2; ns++) {
      #pragma unroll
      for (int reg = 0; reg < 4; reg++) {
        int m = bm + wm + ms * 16 + q * 4 + reg;
        int n = bn + wn + ns * 16 + r;
        if (n < N) {
          float v = acc[ms][ns][reg] + (bias ? bias[n] : 0.f);
          if (EPI == 0) ((float*)Cv)[(size_t)m * ldc + n] = v;
          if (EPI == 2) ((u16*)Cv)[(size_t)m * ldc + n] = f2b(gelu_f(v));
          if (EPI == 3) ((float*)Cv)[(size_t)m * ldc + n] = gelu_f(v) + res[(size_t)m * ldc + n];
        }
      }
    }
  }
}

// ---------------- enc GEMM split-K: A[1024][3136]bf16 @ Wt[128][3136] -> Cp[7][1024][128] f32 ----
__global__ __launch_bounds__(256) void enc_gemm(const u16* __restrict__ A,
    const u16* __restrict__ Wt, float* __restrict__ Cp) {
  __shared__ u16 As[64][40];
  __shared__ u16 Bs[64][40];
  int tid = threadIdx.x;
  int bn = blockIdx.x * 64, bm = blockIdx.y * 64, kc = blockIdx.z;
  int lane = tid & 63, w = tid >> 6;
  int q = lane >> 4, r = lane & 15;
  int wm = (w >> 1) * 32, wn = (w & 1) * 32;
  int am = tid >> 2, ak = (tid & 3) * 8;
  f32x4 acc[2][2] = {};
  int kend = kc * 448 + 448;
  for (int k0 = kc * 448; k0 < kend; k0 += 32) {
    *(short8v*)&As[am][ak] = *(const short8v*)(A + (size_t)(bm + am) * 3136 + k0 + ak);
    *(short8v*)&Bs[am][ak] = *(const short8v*)(Wt + (size_t)(bn + am) * 3136 + k0 + ak);
    __syncthreads();
    short8v a0 = *(const short8v*)&As[wm + r][q * 8];
    short8v a1 = *(const short8v*)&As[wm + 16 + r][q * 8];
    short8v b0 = *(const short8v*)&Bs[wn + r][q * 8];
    short8v b1 = *(const short8v*)&Bs[wn + 16 + r][q * 8];
    acc[0][0] = __builtin_amdgcn_mfma_f32_16x16x32_bf16(a0, b0, acc[0][0], 0, 0, 0);
    acc[0][1] = __builtin_amdgcn_mfma_f32_16x16x32_bf16(a0, b1, acc[0][1], 0, 0, 0);
    acc[1][0] = __builtin_amdgcn_mfma_f32_16x16x32_bf16(a1, b0, acc[1][0], 0, 0, 0);
    acc[1][1] = __builtin_amdgcn_mfma_f32_16x16x32_bf16(a1, b1, acc[1][1], 0, 0, 0);
    __syncthreads();
  }
  #pragma unroll
  for (int ms = 0; ms < 2; ms++)
    #pragma unroll
    for (int ns = 0; ns < 2; ns++)
      #pragma unroll
      for (int reg = 0; reg < 4; reg++) {
        int m = bm + wm + ms * 16 + q * 4 + reg;
        int n = bn + wn + ns * 16 + r;
        Cp[(size_t)(kc * 1024 + m) * 128 + n] = acc[ms][ns][reg];
      }
}

// ---------------- enc reduce + embeddings -> uin (bf16) ----------------
__global__ __launch_bounds__(256) void embedred_k(const float* __restrict__ Cp,
    const float* __restrict__ enc_lb, const int* __restrict__ actions,
    const float* __restrict__ rtgs, const float* __restrict__ act_emb,
    const float* __restrict__ ret_w, const float* __restrict__ ret_b,
    u16* __restrict__ uin) {
  int f = blockIdx.x;
  int b = f >> 7, s = f & 127;
  int e = threadIdx.x;
  if (e < 128) {
    float sum = enc_lb[e];
    #pragma unroll
    for (int kc = 0; kc < 7; kc++) sum += Cp[(size_t)(kc * 1024 + f) * 128 + e];
    uin[(size_t)f * 384 + e] = f2b(tanhf(sum));
    uin[(size_t)f * 384 + 256 + e] =
        f2b(tanhf(fmaf(rtgs[b * Tq + s], ret_w[e], ret_b[e])));
  } else {
    int ee = e - 128;
    int a = actions[b * Tq + s];
    uin[(size_t)f * 384 + 128 + ee] = f2b(tanhf(act_emb[a * NEq + ee]));
  }
}

// ---------------- conv1 MFMA: [4,84,84]f32 -> [400 pos][32 oc]bf16, k8 s4, ReLU -------
__global__ __launch_bounds__(512) void conv1_mfma(const float* __restrict__ states,
    const u16* __restrict__ B1t, const float* __restrict__ bias, u16* __restrict__ out) {
  __shared__ u16 lds[28224];            // [ic][84][84] bf16
  int fr = blockIdx.x;
  int b = fr >> 7, s = fr & 127;
  const float* in = states + (size_t)(b * Tq + s + 1) * 28224;
  int tid = threadIdx.x;
  #pragma unroll
  for (int it = 0; it < 14; it++) {
    int idx = tid + it * 512;
    if (idx < 7056) {
      float4 v = ((const float4*)in)[idx];
      ushort4 uv;
      uv.x = f2b(v.x); uv.y = f2b(v.y); uv.z = f2b(v.z); uv.w = f2b(v.w);
      *(ushort4*)&lds[idx * 4] = uv;
    }
  }
  int lane = tid & 63, w = tid >> 6;
  int q = lane >> 4, r = lane & 15;
  short8v bfr[2][8];
  #pragma unroll
  for (int nt = 0; nt < 2; nt++)
    #pragma unroll
    for (int ks = 0; ks < 8; ks++)
      bfr[nt][ks] = *(const short8v*)(B1t + (nt * 16 + r) * 256 + ks * 32 + q * 8);
  __syncthreads();
  for (int mt = w; mt < 25; mt += 8) {
    int m = mt * 16 + r;
    int oy = m / 20, ox = m % 20;
    f32x4 acc0 = {0.f, 0.f, 0.f, 0.f}, acc1 = {0.f, 0.f, 0.f, 0.f};
    #pragma unroll
    for (int ks = 0; ks < 8; ks++) {
      int k0 = ks * 32 + q * 8;
      int ic = k0 >> 6, ky = (k0 >> 3) & 7;
      int ai = ic * 7056 + (oy * 4 + ky) * 84 + ox * 4;
      ushort4 lo = *(const ushort4*)&lds[ai];
      ushort4 hi = *(const ushort4*)&lds[ai + 4];
      short8v av;
      av[0] = (short)lo.x; av[1] = (short)lo.y; av[2] = (short)lo.z; av[3] = (short)lo.w;
      av[4] = (short)hi.x; av[5] = (short)hi.y; av[6] = (short)hi.z; av[7] = (short)hi.w;
      acc0 = __builtin_amdgcn_mfma_f32_16x16x32_bf16(av, bfr[0][ks], acc0, 0, 0, 0);
      acc1 = __builtin_amdgcn_mfma_f32_16x16x32_bf16(av, bfr[1][ks], acc1, 0, 0, 0);
    }
    #pragma unroll
    for (int reg = 0; reg < 4; reg++) {
      int pos = mt * 16 + q * 4 + reg;
      out[(size_t)fr * 12800 + pos * 32 + r]      = f2b(fmaxf(acc0[reg] + bias[r], 0.f));
      out[(size_t)fr * 12800 + pos * 32 + 16 + r] = f2b(fmaxf(acc1[reg] + bias[16 + r], 0.f));
    }
  }
}

// ---------------- conv2 MFMA: [20,20,32]bf16 -> [81 pos][64 oc]bf16, k4 s2, ReLU ------
__global__ __launch_bounds__(256) void conv2_mfma(const u16* __restrict__ in_,
    const u16* __restrict__ B2t, const float* __restrict__ bias, u16* __restrict__ out) {
  __shared__ u16 lds[12800];
  int fr = blockIdx.x;
  int tid = threadIdx.x;
  const short8v* src = (const short8v*)(in_ + (size_t)fr * 12800);
  short8v* dst = (short8v*)lds;
  #pragma unroll
  for (int it = 0; it < 7; it++) {
    int idx = tid + it * 256;
    if (idx < 1600) dst[idx] = src[idx];
  }
  int lane = tid & 63, w = tid >> 6;
  int q = lane >> 4, r = lane & 15;
  int n = w * 16 + r;
  short8v bfr[16];
  #pragma unroll
  for (int ks = 0; ks < 16; ks++)
    bfr[ks] = *(const short8v*)(B2t + n * 512 + ks * 32 + q * 8);
  __syncthreads();
  float bn = bias[n];
  #pragma unroll
  for (int mt = 0; mt < 6; mt++) {
    int m = mt * 16 + r; if (m > 80) m = 80;
    int oy = m / 9, ox = m % 9;
    f32x4 acc = {0.f, 0.f, 0.f, 0.f};
    #pragma unroll
    for (int ks = 0; ks < 16; ks++) {
      int ky = ks >> 2, kx = ks & 3;
      int ai = ((oy * 2 + ky) * 20 + ox * 2 + kx) * 32 + q * 8;
      short8v av = *(const short8v*)&lds[ai];
      acc = __builtin_amdgcn_mfma_f32_16x16x32_bf16(av, bfr[ks], acc, 0, 0, 0);
    }
    #pragma unroll
    for (int reg = 0; reg < 4; reg++) {
      int pos = mt * 16 + q * 4 + reg;
      if (pos < 81)
        out[(size_t)fr * 5184 + pos * 64 + n] = f2b(fmaxf(acc[reg] + bn, 0.f));
    }
  }
}

// ---------------- conv3 MFMA: [9,9,64]bf16 -> bf16 [oc=64][49 pos], k3 s1, ReLU -------
__global__ __launch_bounds__(256) void conv3_mfma(const u16* __restrict__ in_,
    const u16* __restrict__ B3t, const float* __restrict__ bias, u16* __restrict__ out) {
  __shared__ u16 lds[5184];
  int fr = blockIdx.x;
  int tid = threadIdx.x;
  const short8v* src = (const short8v*)(in_ + (size_t)fr * 5184);
  short8v* dst = (short8v*)lds;
  #pragma unroll
  for (int it = 0; it < 3; it++) {
    int idx = tid + it * 256;
    if (idx < 648) dst[idx] = src[idx];
  }
  int lane = tid & 63, w = tid >> 6;
  int q = lane >> 4, r = lane & 15;
  int n = w * 16 + r;
  short8v bfr[18];
  #pragma unroll
  for (int ks = 0; ks < 18; ks++)
    bfr[ks] = *(const short8v*)(B3t + n * 576 + ks * 32 + q * 8);
  __syncthreads();
  float bn = bias[n];
  #pragma unroll
  for (int mt = 0; mt < 4; mt++) {
    int m = mt * 16 + r; if (m > 48) m = 48;
    int oy = m / 7, ox = m % 7;
    f32x4 acc = {0.f, 0.f, 0.f, 0.f};
    #pragma unroll
    for (int ks = 0; ks < 18; ks++) {
      int kyx = ks >> 1;
      int ky = kyx / 3, kx = kyx % 3;
      int ic0 = (ks & 1) * 32 + q * 8;
      int ai = ((oy + ky) * 9 + ox + kx) * 64 + ic0;
      short8v av = *(const short8v*)&lds[ai];
      acc = __builtin_amdgcn_mfma_f32_16x16x32_bf16(av, bfr[ks], acc, 0, 0, 0);
    }
    #pragma unroll
    for (int reg = 0; reg < 4; reg++) {
      int pos = mt * 16 + q * 4 + reg;
      if (pos < 49)
        out[(size_t)fr * 3136 + n * 49 + pos] = f2b(fmaxf(acc[reg] + bn, 0.f));
    }
  }
}

// ---------------- S4 kernel gen via complex-power recurrence: Ktb[layer][l][h] bf16 ----
__global__ __launch_bounds__(64) void s4k_gen(const float* __restrict__ log_dt,
    const float* __restrict__ A_re, const float* __restrict__ A_im,
    const float* __restrict__ C_re, const float* __restrict__ C_im,
    u16* __restrict__ Ktb) {
  __shared__ float con[64][129];
  int lh = blockIdx.x;            // layer*512 + h
  int n = threadIdx.x;            // 0..63
  float dt = expf(log_dt[lh]);
  float ar = A_re[(size_t)lh * Nq + n], ai = A_im[(size_t)lh * Nq + n];
  float al = dt * ar, be = dt * ai;
  float er = expf(al);
  float wr = er * cosf(be), wi = er * sinf(be);   // w = exp(dt*A)
  float zr = wr - 1.0f, zi = wi;
  float den = 1.0f / (ar * ar + ai * ai);
  float tr = (zr * ar + zi * ai) * den, ti = (zi * ar - zr * ai) * den;
  float Cr = C_re[(size_t)lh * Nq + n], Ci = C_im[(size_t)lh * Nq + n];
  float cr = Cr * tr - Ci * ti, ci = Cr * ti + Ci * tr;
  float curr = 1.0f, curi = 0.0f;
  for (int l = 0; l < Sq; l++) {
    con[n][l] = cr * curr - ci * curi;
    float nr = curr * wr - curi * wi;
    curi = curr * wi + curi * wr;
    curr = nr;
  }
  __syncthreads();
  int layer = lh >> 9, h = lh & 511;
  #pragma unroll
  for (int li = n; li < Sq; li += 64) {
    float s = 0.f;
    for (int j = 0; j < 64; j++) s += con[j][li];
    Ktb[((size_t)layer * Sq + li) * Hq + h] = f2b(2.0f * s);
  }
}

// ---------------- LN row stats: mu, rsqrt(var+eps) per row ----------------
__global__ __launch_bounds__(256) void ln_stats(const float* __restrict__ y,
    float2* __restrict__ stats) {
  int row = blockIdx.x * 4 + (threadIdx.x >> 6);
  int lane = threadIdx.x & 63;
  const float* x = y + (size_t)row * Hq;
  float s = 0.f, s2 = 0.f;
  #pragma unroll
  for (int j = 0; j < 8; j++) {
    float v = x[lane + j * 64];
    s += v; s2 += v * v;
  }
  #pragma unroll
  for (int o = 32; o >= 1; o >>= 1) {
    s += __shfl_xor(s, o);
    s2 += __shfl_xor(s2, o);
  }
  if (lane == 0) {
    float mu = s * (1.f / Hq);
    float var = s2 * (1.f / Hq) - mu * mu;
    stats[row] = make_float2(mu, rsqrtf(var + 1e-5f));
  }
}

// ---------------- fused LN-normalize + causal seq conv + gelu -> bf16 ----------------
// block (hc, b): hc = chunk of 32 h (16 bf16-pairs). Stage K + normalized rows in LDS
// once, then register-window accumulation: thread (p, sg) computes s = 8sg..8sg+7 for
// h-pair p.  c[b,s,h] = D[h]*r[s,h] + sum_{j<=s} K[j,h]*r[s-j,h];  cact = gelu(c) bf16.
__global__ __launch_bounds__(256) void sconv_fused(const float* __restrict__ y,
    const float2* __restrict__ stats, const float* __restrict__ g,
    const float* __restrict__ bta, const u16* __restrict__ Kt,
    const float* __restrict__ D, u16* __restrict__ cact) {
  __shared__ u32 P[16][140];    // [pair][8 zero-pad + 128 s]; stride 140 u32
  __shared__ u32 KL[16][132];   // [pair][j]; stride 132 u32
  int hc = blockIdx.x, b = blockIdx.y;
  int t = threadIdx.x;
  int h0 = hc * 32;
  if (t < 16) {
    #pragma unroll
    for (int i = 0; i < 8; i++) P[t][i] = 0;
  }
  #pragma unroll
  for (int it = 0; it < 8; it++) {
    int idx = it * 256 + t;
    int p = idx & 15, j = idx >> 4;
    KL[p][j] = *(const u32*)(Kt + (size_t)j * Hq + h0 + 2 * p);
  }
  #pragma unroll
  for (int it = 0; it < 8; it++) {
    int idx = it * 256 + t;
    int p = idx & 15, s = idx >> 4;
    int row = b * Sq + s;
    float2 v = *(const float2*)(y + (size_t)row * Hq + h0 + 2 * p);
    float2 st = stats[row];
    float2 gg = *(const float2*)(g + h0 + 2 * p);
    float2 bb = *(const float2*)(bta + h0 + 2 * p);
    float r0 = (v.x - st.x) * st.y * gg.x + bb.x;
    float r1 = (v.y - st.x) * st.y * gg.y + bb.y;
    P[p][8 + s] = (u32)f2b(r0) | ((u32)f2b(r1) << 16);
  }
  __syncthreads();
  int p = t & 15, sg = t >> 4;
  int s0 = sg * 8;
  float acc0[8], acc1[8];
  float2 d2 = *(const float2*)(D + h0 + 2 * p);
  #pragma unroll
  for (int k = 0; k < 8; k++) {
    u32 rv = P[p][8 + s0 + k];
    acc0[k] = d2.x * b2f_lo(rv);
    acc1[k] = d2.y * b2f_hi(rv);
  }
  for (int jb = 0; jb <= sg; jb++) {
    int base = (sg - jb) * 8;               // W = P[p][base .. base+15]
    u32 wv[16], kv[8];
    *(uint4*)&wv[0]  = *(const uint4*)&P[p][base];
    *(uint4*)&wv[4]  = *(const uint4*)&P[p][base + 4];
    *(uint4*)&wv[8]  = *(const uint4*)&P[p][base + 8];
    *(uint4*)&wv[12] = *(const uint4*)&P[p][base + 12];
    *(uint4*)&kv[0]  = *(const uint4*)&KL[p][jb * 8];
    *(uint4*)&kv[4]  = *(const uint4*)&KL[p][jb * 8 + 4];
    float wlo[16], whi[16], klo[8], khi[8];
    #pragma unroll
    for (int i = 0; i < 16; i++) { wlo[i] = b2f_lo(wv[i]); whi[i] = b2f_hi(wv[i]); }
    #pragma unroll
    for (int i = 0; i < 8; i++) { klo[i] = b2f_lo(kv[i]); khi[i] = b2f_hi(kv[i]); }
    #pragma unroll
    for (int jo = 0; jo < 8; jo++)
      #pragma unroll
      for (int k = 0; k < 8; k++) {
        acc0[k] = fmaf(klo[jo], wlo[8 + k - jo], acc0[k]);
        acc1[k] = fmaf(khi[jo], whi[8 + k - jo], acc1[k]);
      }
  }
  #pragma unroll
  for (int k = 0; k < 8; k++) {
    int s = s0 + k;
    u32 outv = (u32)f2b(gelu_f(acc0[k])) | ((u32)f2b(gelu_f(acc1[k])) << 16);
    *(u32*)(cact + ((size_t)(b * Sq + s)) * Hq + h0 + 2 * p) = outv;
  }
}

// ---------------- host ----------------
extern "C" void kernel_launch(void* const* d_in, const int* in_sizes, int n_in,
                              void* d_out, int out_size, void* d_ws, size_t ws_size,
                              hipStream_t stream) {
  const float* states  = (const float*)d_in[0];
  const int*   actions = (const int*)  d_in[1];
  const float* rtgs    = (const float*)d_in[2];
  const float* enc_w1  = (const float*)d_in[3];
  const float* enc_b1  = (const float*)d_in[4];
  const float* enc_w2  = (const float*)d_in[5];
  const float* enc_b2  = (const float*)d_in[6];
  const float* enc_w3  = (const float*)d_in[7];
  const float* enc_b3  = (const float*)d_in[8];
  const float* enc_lw  = (const float*)d_in[9];
  const float* enc_lb  = (const float*)d_in[10];
  const float* ret_w   = (const float*)d_in[11];
  const float* ret_b   = (const float*)d_in[12];
  const float* act_emb = (const float*)d_in[13];
  const float* proj_w  = (const float*)d_in[14];
  const float* proj_b  = (const float*)d_in[15];
  const float* pre_w   = (const float*)d_in[16];
  const float* pre_b   = (const float*)d_in[17];
  const float* ln_g    = (const float*)d_in[18];
  const float* ln_b    = (const float*)d_in[19];
  const float* log_dt  = (const float*)d_in[20];
  const float* A_re    = (const float*)d_in[21];
  const float* A_im    = (const float*)d_in[22];
  const float* C_re    = (const float*)d_in[23];
  const float* C_im    = (const float*)d_in[24];
  const float* Dp      = (const float*)d_in[25];
  const float* aft_w   = (const float*)d_in[26];
  const float* aft_b   = (const float*)d_in[27];
  const float* out_w   = (const float*)d_in[28];

  // workspace layout (u16 units), all regions 16B aligned
  u16* Wt_enc  = (u16*)d_ws;            // 401,408
  u16* Wt_proj = Wt_enc + 401408;       // 196,608
  u16* Wt_pre  = Wt_proj + 196608;      // 262,144
  u16* Wt_aft  = Wt_pre + 262144;       // 1,048,576
  u16* Wt_out  = Wt_aft + 1048576;      // 32,768
  u16* B1t = Wt_out + 32768;            // 8,192
  u16* B2t = B1t + 8192;                // 32,768
  u16* B3t = B2t + 32768;               // 36,864
  u16* o1  = B3t + 36864;               // 13,107,200
  u16* o2  = o1 + 13107200;             // 5,308,416
  u16* x3b = o2 + 5308416;              // 3,211,264
  u16* uin = x3b + 3211264;             // 393,216
  u16* uact = uin + 393216;             // 524,288
  u16* cact = uact + 524288;            // 524,288
  u16* Ktb  = cact + 524288;            // 262,144
  float* y    = (float*)(Ktb + 262144); // 524,288 f32
  float* Cp   = y + 524288;             // 917,504 f32 (7*1024*128)
  float2* stats = (float2*)(Cp + 917504); // 1024 float2

  prep_k<<<778, 256, 0, stream>>>(enc_lw, proj_w, pre_w, aft_w, out_w,
                                  enc_w1, enc_w2, enc_w3,
                                  Wt_enc, Wt_proj, Wt_pre, Wt_aft, Wt_out,
                                  B1t, B2t, B3t);
  conv1_mfma<<<1024, 512, 0, stream>>>(states, B1t, enc_b1, o1);
  conv2_mfma<<<1024, 256, 0, stream>>>(o1, B2t, enc_b2, o2);
  conv3_mfma<<<1024, 256, 0, stream>>>(o2, B3t, enc_b3, x3b);
  // se = tanh(x3 @ enc_lw + enc_lb) -> uin[:, 0:128], via split-K
  enc_gemm<<<dim3(2, 16, 7), 256, 0, stream>>>(x3b, Wt_enc, Cp);
  embedred_k<<<1024, 256, 0, stream>>>(Cp, enc_lb, actions, rtgs, act_emb,
                                       ret_w, ret_b, uin);
  // uact = gelu(uin @ proj_w + proj_b)  (bf16)
  mgemm<false, 2><<<dim3(8, 16), 256, 0, stream>>>(uin, Wt_proj, proj_b, nullptr, uact,
                                                   1024, 384, 512, 512);
  // y = uact @ pre_w + pre_b  (f32)
  mgemm<false, 0><<<dim3(8, 16), 256, 0, stream>>>(uact, Wt_pre, pre_b, nullptr, y,
                                                   1024, 512, 512, 512);
  s4k_gen<<<2048, 64, 0, stream>>>(log_dt, A_re, A_im, C_re, C_im, Ktb);

  for (int i = 0; i < NLq; i++) {
    ln_stats<<<256, 256, 0, stream>>>(y, stats);
    sconv_fused<<<dim3(16, 8), 256, 0, stream>>>(y, stats, ln_g + i * Hq,
                                                 ln_b + i * Hq,
                                                 Ktb + (size_t)i * Sq * Hq,
                                                 Dp + i * Hq, cact);
    // y = gelu(cact @ aft_w + aft_b) + y
    mgemm<false, 3><<<dim3(8, 16), 256, 0, stream>>>(cact, Wt_aft + (size_t)i * Hq * Hq,
                                                     aft_b + i * Hq, y, y,
                                                     1024, 512, 512, 512);
  }
  // logits = y @ out_w  (f32, no bias)
  mgemm<true, 0><<<dim3(1, 16), 256, 0, stream>>>(y, Wt_out, nullptr, nullptr,
                                                  (float*)d_out, 1024, 512, Vq, Vq);
}